// Round 1
// baseline (8991.337 us; speedup 1.0000x reference)
//
#include <hip/hip_runtime.h>

constexpr int kNodes   = 100000;
constexpr int kEdges   = 1600000;
constexpr int kDin     = 128;
constexpr int kDhid    = 256;
constexpr int kClasses = 40;
constexpr int kGraphs  = 64;

constexpr int BM = 64;   // nodes per block tile
constexpr int BN = 128;  // hid cols per block tile (2 blocks cover 256)
constexpr int KC = 16;   // K-chunk

// ---------------------------------------------------------------------------
// Kernel 1: edge scatter. 32 threads per edge, each handles 4 floats (float4).
// agg[dst] += h[src]; deg[dst] += 1.
// ---------------------------------------------------------------------------
__global__ void scatter_edges(const float* __restrict__ h,
                              const int* __restrict__ src,
                              const int* __restrict__ dst,
                              float* __restrict__ agg,
                              float* __restrict__ deg) {
  long long t = (long long)blockIdx.x * blockDim.x + threadIdx.x;
  int e = (int)(t >> 5);
  if (e >= kEdges) return;
  int lane = (int)(t & 31);
  int s = src[e];
  int d = dst[e];
  float4 v = *reinterpret_cast<const float4*>(h + (size_t)s * kDin + lane * 4);
  float* arow = agg + (size_t)d * kDin + lane * 4;
  atomicAdd(arow + 0, v.x);
  atomicAdd(arow + 1, v.y);
  atomicAdd(arow + 2, v.z);
  atomicAdd(arow + 3, v.w);
  if (lane == 0) atomicAdd(deg + d, 1.0f);
}

// ---------------------------------------------------------------------------
// Kernel 2: fused  hid = relu(h@Ws + (agg/deg)@Wn + b)  + per-graph pooling.
// Block tile: 64 nodes x 128 cols, 256 threads, thread tile 4x8.
// graph_ids is sorted -> per block only g0..g1 graphs; LDS-reduce then atomics.
// ---------------------------------------------------------------------------
union alignas(16) SMem {
  struct {
    float A[KC][BM + 4];   // h tile, [k][n], +4 pad keeps 16B align & banks
    float B[KC][BM + 4];   // h_neigh tile
    float Ws[KC][BN];
    float Wn[KC][BN];
  } s;
  float hid[BM][BN];       // reused after K-loop
};

__launch_bounds__(256, 4)
__global__ void gemm_pool(const float* __restrict__ h,
                          const float* __restrict__ Wself,
                          const float* __restrict__ Wneigh,
                          const float* __restrict__ bias,
                          const float* __restrict__ agg,
                          const float* __restrict__ deg,
                          const int* __restrict__ gid,
                          float* __restrict__ gsum) {
  __shared__ SMem sm;
  const int tid = threadIdx.x;
  const int bx = blockIdx.x & 1;
  const int by = blockIdx.x >> 1;
  const int nbase = by * BM;
  const int jbase = bx * BN;
  const int tx = tid & 15;
  const int ty = tid >> 4;

  float acc[4][8];
#pragma unroll
  for (int i = 0; i < 4; ++i)
#pragma unroll
    for (int j = 0; j < 8; ++j) acc[i][j] = 0.f;

  for (int k0 = 0; k0 < kDin; k0 += KC) {
    // stage A (h) and B (agg/deg): 64x16 each, [k][n] layout
#pragma unroll
    for (int it = 0; it < (BM * KC) / 256; ++it) {
      int i = tid + it * 256;
      int k = i & (KC - 1);
      int n = i >> 4;
      int node = nbase + n;
      float va = 0.f, vb = 0.f;
      if (node < kNodes) {
        va = h[(size_t)node * kDin + k0 + k];
        float rd = 1.0f / fmaxf(deg[node], 1.0f);
        vb = agg[(size_t)node * kDin + k0 + k] * rd;
      }
      sm.s.A[k][n] = va;
      sm.s.B[k][n] = vb;
    }
    // stage Ws, Wn: 16x128 each
#pragma unroll
    for (int it = 0; it < (KC * BN) / 256; ++it) {
      int i = tid + it * 256;
      int j = i & (BN - 1);
      int k = i >> 7;
      sm.s.Ws[k][j] = Wself[(size_t)(k0 + k) * kDhid + jbase + j];
      sm.s.Wn[k][j] = Wneigh[(size_t)(k0 + k) * kDhid + jbase + j];
    }
    __syncthreads();
#pragma unroll
    for (int kk = 0; kk < KC; ++kk) {
      float4 a4  = *reinterpret_cast<const float4*>(&sm.s.A[kk][ty * 4]);
      float4 b4  = *reinterpret_cast<const float4*>(&sm.s.B[kk][ty * 4]);
      float4 ws0 = *reinterpret_cast<const float4*>(&sm.s.Ws[kk][tx * 4]);
      float4 ws1 = *reinterpret_cast<const float4*>(&sm.s.Ws[kk][64 + tx * 4]);
      float4 wn0 = *reinterpret_cast<const float4*>(&sm.s.Wn[kk][tx * 4]);
      float4 wn1 = *reinterpret_cast<const float4*>(&sm.s.Wn[kk][64 + tx * 4]);
      float av[4]  = {a4.x, a4.y, a4.z, a4.w};
      float bv[4]  = {b4.x, b4.y, b4.z, b4.w};
      float wsv[8] = {ws0.x, ws0.y, ws0.z, ws0.w, ws1.x, ws1.y, ws1.z, ws1.w};
      float wnv[8] = {wn0.x, wn0.y, wn0.z, wn0.w, wn1.x, wn1.y, wn1.z, wn1.w};
#pragma unroll
      for (int i = 0; i < 4; ++i)
#pragma unroll
        for (int j = 0; j < 8; ++j)
          acc[i][j] += av[i] * wsv[j] + bv[i] * wnv[j];
    }
    __syncthreads();
  }

  // epilogue: bias + relu into LDS hid tile (A/W region dead after last sync)
#pragma unroll
  for (int i = 0; i < 4; ++i) {
    int n = ty * 4 + i;
#pragma unroll
    for (int j = 0; j < 8; ++j) {
      int c = (j < 4) ? (tx * 4 + j) : (64 + tx * 4 + (j - 4));
      float v = acc[i][j] + bias[jbase + c];
      sm.hid[n][c] = fmaxf(v, 0.f);
    }
  }
  __syncthreads();

  // per-graph pooling: graphs in this block span [g0, g1] (gid sorted)
  int lastnode = min(nbase + BM, kNodes) - 1;
  int g0 = gid[nbase];
  int g1 = gid[lastnode];
  int c = tid & (BN - 1);
  int p = tid >> 7;  // 0 or 1, 32 nodes each
  for (int g = g0; g <= g1; ++g) {
    float ssum = 0.f;
    for (int n = p * 32; n < p * 32 + 32; ++n) {
      int node = nbase + n;
      if (node < kNodes && gid[node] == g) ssum += sm.hid[n][c];
    }
    if (ssum != 0.f) atomicAdd(&gsum[g * kDhid + jbase + c], ssum);
  }
}

// ---------------------------------------------------------------------------
// Kernel 3: head. out[g] = (gsum[g]/cnt[g]) @ Wp + bp. cnt via binary search
// on sorted graph_ids. One block per graph.
// ---------------------------------------------------------------------------
__global__ void head_kernel(const float* __restrict__ gsum,
                            const float* __restrict__ Wp,
                            const float* __restrict__ bp,
                            const int* __restrict__ gid,
                            float* __restrict__ out) {
  int g = blockIdx.x;
  int c = threadIdx.x;
  // lower_bound(g) and lower_bound(g+1)
  int lo0 = 0, hi0 = kNodes;
  while (lo0 < hi0) { int m = (lo0 + hi0) >> 1; if (gid[m] < g) lo0 = m + 1; else hi0 = m; }
  int lo1 = lo0, hi1 = kNodes;
  while (lo1 < hi1) { int m = (lo1 + hi1) >> 1; if (gid[m] < g + 1) lo1 = m + 1; else hi1 = m; }
  float rc = 1.0f / fmaxf((float)(hi1 - lo0 > 0 ? lo1 - lo0 : 0), 1.0f);
  if (c < kClasses) {
    float acc = bp[c];
    for (int k = 0; k < kDhid; ++k)
      acc += gsum[g * kDhid + k] * rc * Wp[k * kClasses + c];
    out[g * kClasses + c] = acc;
  }
}

// ---------------------------------------------------------------------------
extern "C" void kernel_launch(void* const* d_in, const int* in_sizes, int n_in,
                              void* d_out, int out_size, void* d_ws, size_t ws_size,
                              hipStream_t stream) {
  const float* h  = (const float*)d_in[0];
  const float* Ws = (const float*)d_in[1];
  const float* Wn = (const float*)d_in[2];
  const float* b  = (const float*)d_in[3];
  const float* Wp = (const float*)d_in[4];
  const float* bp = (const float*)d_in[5];
  const int* src  = (const int*)d_in[6];
  const int* dst  = (const int*)d_in[7];
  const int* gid  = (const int*)d_in[8];
  float* out = (float*)d_out;

  char* ws = (char*)d_ws;
  const size_t aggBytes = (size_t)kNodes * kDin * sizeof(float);   // 51.2 MB
  const size_t degBytes = (size_t)kNodes * sizeof(float);
  const size_t gsumBytes = (size_t)kGraphs * kDhid * sizeof(float);
  float* agg  = (float*)ws;
  float* deg  = (float*)(ws + aggBytes);
  float* gsum = (float*)(ws + aggBytes + degBytes);

  hipMemsetAsync(d_ws, 0, aggBytes + degBytes + gsumBytes, stream);

  {
    long long threads = (long long)kEdges * 32;
    int blk = 256;
    long long nblocks = (threads + blk - 1) / blk;
    hipLaunchKernelGGL(scatter_edges, dim3((unsigned)nblocks), dim3(blk), 0, stream,
                       h, src, dst, agg, deg);
  }
  {
    int nblocks = ((kNodes + BM - 1) / BM) * (kDhid / BN);
    hipLaunchKernelGGL(gemm_pool, dim3(nblocks), dim3(256), 0, stream,
                       h, Ws, Wn, b, agg, deg, gid, gsum);
  }
  hipLaunchKernelGGL(head_kernel, dim3(kGraphs), dim3(64), 0, stream,
                     gsum, Wp, bp, gid, out);
}

// Round 2
// 1690.305 us; speedup vs baseline: 5.3194x; 5.3194x over previous
//
#include <hip/hip_runtime.h>

constexpr int kNodes   = 100000;
constexpr int kEdges   = 1600000;
constexpr int kDin     = 128;
constexpr int kDhid    = 256;
constexpr int kClasses = 40;
constexpr int kGraphs  = 64;

constexpr int BM = 64;   // nodes per block tile
constexpr int BN = 128;  // hid cols per block tile (2 blocks cover 256)
constexpr int KC = 16;   // K-chunk

// ---------------------------------------------------------------------------
// CSR build: count -> scan -> fill
// ---------------------------------------------------------------------------
__global__ void count_deg(const int* __restrict__ dst, int* __restrict__ row) {
  int e = blockIdx.x * blockDim.x + threadIdx.x;
  if (e < kEdges) atomicAdd(&row[dst[e] + 1], 1);
}

__global__ void scan_offsets(int* __restrict__ row) {
  // inclusive scan over row[0..kNodes], single block of 1024 threads
  const int N1 = kNodes + 1;
  const int T = 1024;
  __shared__ int part[T];
  int t = threadIdx.x;
  int chunk = (N1 + T - 1) / T;  // 98
  int lo = t * chunk, hi = min(lo + chunk, N1);
  int s = 0;
  for (int i = lo; i < hi; ++i) s += row[i];
  part[t] = s;
  __syncthreads();
  for (int off = 1; off < T; off <<= 1) {
    int v = (t >= off) ? part[t - off] : 0;
    __syncthreads();
    part[t] += v;
    __syncthreads();
  }
  int pre = (t == 0) ? 0 : part[t - 1];
  for (int i = lo; i < hi; ++i) { pre += row[i]; row[i] = pre; }
}

__global__ void fill_csr(const int* __restrict__ src, const int* __restrict__ dst,
                         const int* __restrict__ row, int* __restrict__ cursor,
                         int* __restrict__ csr) {
  int e = blockIdx.x * blockDim.x + threadIdx.x;
  if (e >= kEdges) return;
  int d = dst[e];
  int pos = atomicAdd(&cursor[d], 1);
  csr[row[d] + pos] = src[e];
}

// ---------------------------------------------------------------------------
// Gather-aggregate: h_neigh[n] = mean over in-neighbors of h.  One wave/node,
// lane owns 2 floats (float2).  4 nodes per 256-thread block.
// ---------------------------------------------------------------------------
__global__ void aggregate(const float* __restrict__ h, const int* __restrict__ row,
                          const int* __restrict__ csr, float* __restrict__ hn) {
  int n = blockIdx.x * 4 + (threadIdx.x >> 6);
  if (n >= kNodes) return;
  int lane = threadIdx.x & 63;
  int s0 = row[n], s1 = row[n + 1];
  float ax = 0.f, ay = 0.f;
  for (int i = s0; i < s1; ++i) {
    int s = csr[i];
    const float2 v = *reinterpret_cast<const float2*>(h + (size_t)s * kDin + lane * 2);
    ax += v.x; ay += v.y;
  }
  float rd = 1.0f / fmaxf((float)(s1 - s0), 1.0f);
  *reinterpret_cast<float2*>(hn + (size_t)n * kDin + lane * 2) = make_float2(ax * rd, ay * rd);
}

// ---------------------------------------------------------------------------
// Fused  hid = relu(h@Ws + hn@Wn + b)  + per-graph pooling (gid sorted).
// Block tile 64x128, 256 threads, thread tile 4x8.
// ---------------------------------------------------------------------------
union alignas(16) SMem {
  struct {
    float A[KC][BM + 4];
    float B[KC][BM + 4];
    float Ws[KC][BN];
    float Wn[KC][BN];
  } s;
  float hid[BM][BN];
};

__launch_bounds__(256, 2)
__global__ void gemm_pool(const float* __restrict__ h,
                          const float* __restrict__ Wself,
                          const float* __restrict__ Wneigh,
                          const float* __restrict__ bias,
                          const float* __restrict__ hn,
                          const int* __restrict__ gid,
                          float* __restrict__ gsum) {
  __shared__ SMem sm;
  const int tid = threadIdx.x;
  const int bx = blockIdx.x & 1;
  const int by = blockIdx.x >> 1;
  const int nbase = by * BM;
  const int jbase = bx * BN;
  const int tx = tid & 15;
  const int ty = tid >> 4;

  float acc[4][8];
#pragma unroll
  for (int i = 0; i < 4; ++i)
#pragma unroll
    for (int j = 0; j < 8; ++j) acc[i][j] = 0.f;

  for (int k0 = 0; k0 < kDin; k0 += KC) {
    // stage A (h) and B (hn): 64 nodes x 16 k, float4 per thread
    {
      int n = tid >> 2;          // 0..63
      int kq = (tid & 3) * 4;    // 0,4,8,12
      int node = nbase + n;
      float4 va = make_float4(0.f, 0.f, 0.f, 0.f);
      float4 vb = va;
      if (node < kNodes) {
        va = *reinterpret_cast<const float4*>(h + (size_t)node * kDin + k0 + kq);
        vb = *reinterpret_cast<const float4*>(hn + (size_t)node * kDin + k0 + kq);
      }
      sm.s.A[kq + 0][n] = va.x; sm.s.A[kq + 1][n] = va.y;
      sm.s.A[kq + 2][n] = va.z; sm.s.A[kq + 3][n] = va.w;
      sm.s.B[kq + 0][n] = vb.x; sm.s.B[kq + 1][n] = vb.y;
      sm.s.B[kq + 2][n] = vb.z; sm.s.B[kq + 3][n] = vb.w;
    }
    // stage Ws, Wn: 16 k x 128 cols, two float4 per thread each
    {
      int j4 = (tid & 31) * 4;
      int k = tid >> 5;  // 0..7
#pragma unroll
      for (int kk2 = 0; kk2 < 2; ++kk2) {
        int kr = k + kk2 * 8;
        *reinterpret_cast<float4*>(&sm.s.Ws[kr][j4]) =
            *reinterpret_cast<const float4*>(Wself + (size_t)(k0 + kr) * kDhid + jbase + j4);
        *reinterpret_cast<float4*>(&sm.s.Wn[kr][j4]) =
            *reinterpret_cast<const float4*>(Wneigh + (size_t)(k0 + kr) * kDhid + jbase + j4);
      }
    }
    __syncthreads();
#pragma unroll
    for (int kk = 0; kk < KC; ++kk) {
      float4 a4  = *reinterpret_cast<const float4*>(&sm.s.A[kk][ty * 4]);
      float4 b4  = *reinterpret_cast<const float4*>(&sm.s.B[kk][ty * 4]);
      float4 ws0 = *reinterpret_cast<const float4*>(&sm.s.Ws[kk][tx * 4]);
      float4 ws1 = *reinterpret_cast<const float4*>(&sm.s.Ws[kk][64 + tx * 4]);
      float4 wn0 = *reinterpret_cast<const float4*>(&sm.s.Wn[kk][tx * 4]);
      float4 wn1 = *reinterpret_cast<const float4*>(&sm.s.Wn[kk][64 + tx * 4]);
      float av[4]  = {a4.x, a4.y, a4.z, a4.w};
      float bv[4]  = {b4.x, b4.y, b4.z, b4.w};
      float wsv[8] = {ws0.x, ws0.y, ws0.z, ws0.w, ws1.x, ws1.y, ws1.z, ws1.w};
      float wnv[8] = {wn0.x, wn0.y, wn0.z, wn0.w, wn1.x, wn1.y, wn1.z, wn1.w};
#pragma unroll
      for (int i = 0; i < 4; ++i)
#pragma unroll
        for (int j = 0; j < 8; ++j)
          acc[i][j] += av[i] * wsv[j] + bv[i] * wnv[j];
    }
    __syncthreads();
  }

  // epilogue: bias + relu into LDS hid tile (staging region dead)
#pragma unroll
  for (int i = 0; i < 4; ++i) {
    int n = ty * 4 + i;
#pragma unroll
    for (int j = 0; j < 8; ++j) {
      int c = (j < 4) ? (tx * 4 + j) : (64 + tx * 4 + (j - 4));
      float v = acc[i][j] + bias[jbase + c];
      sm.hid[n][c] = fmaxf(v, 0.f);
    }
  }
  __syncthreads();

  // per-graph pooling: graphs in this block span [g0, g1] (gid sorted)
  int lastnode = min(nbase + BM, kNodes) - 1;
  int g0 = gid[nbase];
  int g1 = gid[lastnode];
  int c = tid & (BN - 1);
  int p = tid >> 7;  // 0 or 1, 32 nodes each
  for (int g = g0; g <= g1; ++g) {
    float ssum = 0.f;
    for (int n = p * 32; n < p * 32 + 32; ++n) {
      int node = nbase + n;
      if (node < kNodes && gid[node] == g) ssum += sm.hid[n][c];
    }
    if (ssum != 0.f) atomicAdd(&gsum[g * kDhid + jbase + c], ssum);
  }
}

// ---------------------------------------------------------------------------
// Head: out[g] = (gsum[g]/cnt[g]) @ Wp + bp.  cnt via binary search on gid.
// ---------------------------------------------------------------------------
__global__ void head_kernel(const float* __restrict__ gsum,
                            const float* __restrict__ Wp,
                            const float* __restrict__ bp,
                            const int* __restrict__ gid,
                            float* __restrict__ out) {
  int g = blockIdx.x;
  int c = threadIdx.x;
  int lo0 = 0, hi0 = kNodes;
  while (lo0 < hi0) { int m = (lo0 + hi0) >> 1; if (gid[m] < g) lo0 = m + 1; else hi0 = m; }
  int lo1 = lo0, hi1 = kNodes;
  while (lo1 < hi1) { int m = (lo1 + hi1) >> 1; if (gid[m] < g + 1) lo1 = m + 1; else hi1 = m; }
  float rc = 1.0f / fmaxf((float)(lo1 - lo0), 1.0f);
  if (c < kClasses) {
    float acc = bp[c];
    for (int k = 0; k < kDhid; ++k)
      acc += gsum[g * kDhid + k] * rc * Wp[k * kClasses + c];
    out[g * kClasses + c] = acc;
  }
}

// ---------------------------------------------------------------------------
extern "C" void kernel_launch(void* const* d_in, const int* in_sizes, int n_in,
                              void* d_out, int out_size, void* d_ws, size_t ws_size,
                              hipStream_t stream) {
  const float* h  = (const float*)d_in[0];
  const float* Ws = (const float*)d_in[1];
  const float* Wn = (const float*)d_in[2];
  const float* b  = (const float*)d_in[3];
  const float* Wp = (const float*)d_in[4];
  const float* bp = (const float*)d_in[5];
  const int* src  = (const int*)d_in[6];
  const int* dst  = (const int*)d_in[7];
  const int* gid  = (const int*)d_in[8];
  float* out = (float*)d_out;

  char* ws = (char*)d_ws;
  const size_t hnOff     = 0;                          // 51,200,000 B
  const size_t csrOff    = 51200000;                   // 6,400,000 B
  const size_t rowOff    = 57600000;                   // 400,016 B (padded)
  const size_t curOff    = 58000016;                   // 400,000 B
  const size_t gsumOff   = 58400016;                   // 65,536 B
  float* hn   = (float*)(ws + hnOff);
  int* csr    = (int*)(ws + csrOff);
  int* row    = (int*)(ws + rowOff);
  int* cursor = (int*)(ws + curOff);
  float* gsum = (float*)(ws + gsumOff);

  // zero row, cursor, gsum in one shot (contiguous region)
  hipMemsetAsync(ws + rowOff, 0, (58400016 + 65536) - 57600000, stream);

  int eblk = (kEdges + 255) / 256;
  hipLaunchKernelGGL(count_deg, dim3(eblk), dim3(256), 0, stream, dst, row);
  hipLaunchKernelGGL(scan_offsets, dim3(1), dim3(1024), 0, stream, row);
  hipLaunchKernelGGL(fill_csr, dim3(eblk), dim3(256), 0, stream, src, dst, row, cursor, csr);
  hipLaunchKernelGGL(aggregate, dim3((kNodes + 3) / 4), dim3(256), 0, stream, h, row, csr, hn);

  int nblocks = ((kNodes + BM - 1) / BM) * (kDhid / BN);
  hipLaunchKernelGGL(gemm_pool, dim3(nblocks), dim3(256), 0, stream,
                     h, Ws, Wn, b, hn, gid, gsum);
  hipLaunchKernelGGL(head_kernel, dim3(kGraphs), dim3(64), 0, stream,
                     gsum, Wp, bp, gid, out);
}

// Round 3
// 589.342 us; speedup vs baseline: 15.2566x; 2.8681x over previous
//
#include <hip/hip_runtime.h>
#include <stdint.h>

constexpr int kNodes    = 100000;
constexpr int kNodesPad = 100096;   // 782 * 128
constexpr int kEdges    = 1600000;
constexpr int kDin      = 128;
constexpr int kK        = 256;      // concat K = [h | h_neigh]
constexpr int kDhid     = 256;
constexpr int kClasses  = 40;
constexpr int kGraphs   = 64;

typedef __attribute__((ext_vector_type(8))) short bf8_t;   // 8 x bf16 (4 VGPR)
typedef __attribute__((ext_vector_type(4))) float f4_t;    // mfma C/D

__device__ inline ushort f2bf(float f) {
  uint32_t u = __float_as_uint(f);
  u += 0x7fff + ((u >> 16) & 1);          // RNE
  return (ushort)(u >> 16);
}
__device__ inline float bf2f(ushort b) { return __uint_as_float(((uint32_t)b) << 16); }

// ---------------------------------------------------------------------------
// CSR build: count -> scan -> fill
// ---------------------------------------------------------------------------
__global__ void count_deg(const int* __restrict__ dst, int* __restrict__ row) {
  int e = blockIdx.x * blockDim.x + threadIdx.x;
  if (e < kEdges) atomicAdd(&row[dst[e] + 1], 1);
}

__global__ void scan_offsets(int* __restrict__ row) {
  const int N1 = kNodes + 1;
  const int T = 1024;
  __shared__ int part[T];
  int t = threadIdx.x;
  int chunk = (N1 + T - 1) / T;
  int lo = t * chunk, hi = min(lo + chunk, N1);
  int s = 0;
  for (int i = lo; i < hi; ++i) s += row[i];
  part[t] = s;
  __syncthreads();
  for (int off = 1; off < T; off <<= 1) {
    int v = (t >= off) ? part[t - off] : 0;
    __syncthreads();
    part[t] += v;
    __syncthreads();
  }
  int pre = (t == 0) ? 0 : part[t - 1];
  for (int i = lo; i < hi; ++i) { pre += row[i]; row[i] = pre; }
}

__global__ void fill_csr(const int* __restrict__ src, const int* __restrict__ dst,
                         const int* __restrict__ row, int* __restrict__ cursor,
                         int* __restrict__ csr) {
  int e = blockIdx.x * blockDim.x + threadIdx.x;
  if (e >= kEdges) return;
  int d = dst[e];
  int pos = atomicAdd(&cursor[d], 1);
  csr[row[d] + pos] = src[e];
}

// ---------------------------------------------------------------------------
// cvt_h: h fp32 -> A16[n][0..127] bf16 (zeros for padded rows)
// ---------------------------------------------------------------------------
__global__ void cvt_h(const float* __restrict__ h, ushort* __restrict__ A16) {
  int t = blockIdx.x * blockDim.x + threadIdx.x;
  if (t >= kNodesPad * 32) return;
  int n = t >> 5;
  int c4 = (t & 31) * 4;
  float4 v = make_float4(0.f, 0.f, 0.f, 0.f);
  if (n < kNodes) v = *reinterpret_cast<const float4*>(h + (size_t)n * kDin + c4);
  ushort4 o;
  o.x = f2bf(v.x); o.y = f2bf(v.y); o.z = f2bf(v.z); o.w = f2bf(v.w);
  *reinterpret_cast<ushort4*>(A16 + (size_t)n * kK + c4) = o;
}

// ---------------------------------------------------------------------------
// cvt_w: Wt[j][k] = bf16( k<128 ? Ws[k][j] : Wn[k-128][j] )   (transposed)
// ---------------------------------------------------------------------------
__global__ void cvt_w(const float* __restrict__ Ws, const float* __restrict__ Wn,
                      ushort* __restrict__ Wt) {
  int t = blockIdx.x * blockDim.x + threadIdx.x;
  if (t >= kK * kDhid) return;
  int j = t & 255;
  int k = t >> 8;
  float v = (k < 128) ? Ws[(size_t)k * kDhid + j] : Wn[(size_t)(k - 128) * kDhid + j];
  Wt[(size_t)j * kK + k] = f2bf(v);
}

// ---------------------------------------------------------------------------
// aggregate: A16[n][128..255] = bf16( mean over in-neighbors of A16[s][0..127] )
// one wave per node; lane owns 2 bf16 (one dword).
// ---------------------------------------------------------------------------
__global__ void aggregate(ushort* __restrict__ A16, const int* __restrict__ row,
                          const int* __restrict__ csr) {
  int n = blockIdx.x * 4 + (threadIdx.x >> 6);
  if (n >= kNodesPad) return;
  int lane = threadIdx.x & 63;
  uint32_t* outp = (uint32_t*)(A16 + (size_t)n * kK + kDin) + lane;
  if (n >= kNodes) { *outp = 0u; return; }
  int s0 = row[n], s1 = row[n + 1];
  float ax = 0.f, ay = 0.f;
  for (int i = s0; i < s1; ++i) {
    int s = csr[i];
    uint32_t v = *((const uint32_t*)(A16 + (size_t)s * kK) + lane);
    ax += bf2f((ushort)(v & 0xffffu));
    ay += bf2f((ushort)(v >> 16));
  }
  float rd = 1.f / fmaxf((float)(s1 - s0), 1.f);
  *outp = (uint32_t)f2bf(ax * rd) | ((uint32_t)f2bf(ay * rd) << 16);
}

// ---------------------------------------------------------------------------
// gemm_pool: hid = relu(A16 @ Wt^T + b) fused with per-graph pooling.
// 128x128 tile, 4 waves, mfma_f32_16x16x32_bf16, K=256 in two 128-steps.
// LDS tiles [128 rows][128 k] bf16, XOR-swizzled (T2) via pre-swizzled
// global source (global_load_lds writes linearly; rule #21).
// ---------------------------------------------------------------------------
__global__ __launch_bounds__(256, 2)
void gemm_pool(const ushort* __restrict__ A16, const ushort* __restrict__ Wt,
               const float* __restrict__ bias, const int* __restrict__ gid,
               float* __restrict__ gsum) {
  __shared__ union {
    struct { ushort A[128 * 128]; ushort B[128 * 128]; } st;  // 32KB + 32KB
    float hid[128][128];                                      // 64KB (reused)
  } sm;
  const int tid  = threadIdx.x;
  const int lane = tid & 63;
  const int wave = tid >> 6;
  const int wr = wave >> 1, wc = wave & 1;
  const int cb = blockIdx.x & 1;
  const int rb = blockIdx.x >> 1;
  const int nbase = rb * 128;
  const int jbase = cb * 128;
  const int lhi = lane >> 4;   // 0..3
  const int llo = lane & 15;

  f4_t acc[4][4];
#pragma unroll
  for (int i = 0; i < 4; ++i)
#pragma unroll
    for (int j = 0; j < 4; ++j) acc[i][j] = (f4_t)0.f;

  for (int k0 = 0; k0 < 2; ++k0) {   // K offset = k0*128
    // ---- stage A and B tiles: each wave 8 segments x 1KB each ----
#pragma unroll
    for (int s = 0; s < 8; ++s) {
      int r = wave * 32 + s * 4 + lhi;                 // tile row this lane feeds
      int swz = (llo * 16) ^ ((r & 7) << 4);           // inverse-swizzled source col
      size_t ga = (size_t)(nbase + r) * 512 + (size_t)k0 * 256 + swz;
      size_t gb = (size_t)(jbase + r) * 512 + (size_t)k0 * 256 + swz;
      uint32_t ldsOff = (uint32_t)(wave * 32 + s * 4) * 256;  // bytes, wave-uniform
      __builtin_amdgcn_global_load_lds(
          (const __attribute__((address_space(1))) uint32_t*)((const char*)A16 + ga),
          (__attribute__((address_space(3))) uint32_t*)((char*)sm.st.A + ldsOff),
          16, 0, 0);
      __builtin_amdgcn_global_load_lds(
          (const __attribute__((address_space(1))) uint32_t*)((const char*)Wt + gb),
          (__attribute__((address_space(3))) uint32_t*)((char*)sm.st.B + ldsOff),
          16, 0, 0);
    }
    __syncthreads();
    // ---- compute: 4 k-slices of 32 ----
#pragma unroll
    for (int kh = 0; kh < 4; ++kh) {
      const int kb = kh * 64 + lhi * 16;               // byte offset of this lane's k-octet
      bf8_t av[4], bv[4];
#pragma unroll
      for (int mf = 0; mf < 4; ++mf) {
        int m = wr * 64 + mf * 16 + llo;
        av[mf] = *reinterpret_cast<const bf8_t*>(
            (const char*)sm.st.A + m * 256 + (kb ^ ((m & 7) << 4)));
      }
#pragma unroll
      for (int nf = 0; nf < 4; ++nf) {
        int j = wc * 64 + nf * 16 + llo;
        bv[nf] = *reinterpret_cast<const bf8_t*>(
            (const char*)sm.st.B + j * 256 + (kb ^ ((j & 7) << 4)));
      }
#pragma unroll
      for (int mf = 0; mf < 4; ++mf)
#pragma unroll
        for (int nf = 0; nf < 4; ++nf)
          acc[mf][nf] = __builtin_amdgcn_mfma_f32_16x16x32_bf16(av[mf], bv[nf], acc[mf][nf], 0, 0, 0);
    }
    __syncthreads();
  }

  // ---- epilogue: bias + relu into LDS hid tile ----
  float bvv[4];
#pragma unroll
  for (int nf = 0; nf < 4; ++nf) bvv[nf] = bias[jbase + wc * 64 + nf * 16 + llo];
#pragma unroll
  for (int mf = 0; mf < 4; ++mf)
#pragma unroll
    for (int nf = 0; nf < 4; ++nf) {
      int col = wc * 64 + nf * 16 + llo;
#pragma unroll
      for (int q = 0; q < 4; ++q) {
        int rowi = wr * 64 + mf * 16 + lhi * 4 + q;    // C/D: col=lane&15, row=(lane>>4)*4+q
        sm.hid[rowi][col] = fmaxf(acc[mf][nf][q] + bvv[nf], 0.f);
      }
    }
  __syncthreads();

  // ---- per-graph pooling (gid sorted) ----
  int lastnode = min(nbase + 128, kNodes) - 1;
  int g0 = gid[nbase];
  int g1 = gid[lastnode];
  int c = tid & 127;
  int half = tid >> 7;
  for (int g = g0; g <= g1; ++g) {
    float sacc = 0.f;
    for (int r = half * 64; r < half * 64 + 64; ++r) {
      int node = nbase + r;
      if (node < kNodes && gid[node] == g) sacc += sm.hid[r][c];
    }
    if (sacc != 0.f) atomicAdd(&gsum[g * kDhid + jbase + c], sacc);
  }
}

// ---------------------------------------------------------------------------
// head: out[g] = (gsum[g]/cnt[g]) @ Wp + bp, cnt via binary search on gid.
// ---------------------------------------------------------------------------
__global__ void head_kernel(const float* __restrict__ gsum,
                            const float* __restrict__ Wp,
                            const float* __restrict__ bp,
                            const int* __restrict__ gid,
                            float* __restrict__ out) {
  int g = blockIdx.x;
  int c = threadIdx.x;
  int lo0 = 0, hi0 = kNodes;
  while (lo0 < hi0) { int m = (lo0 + hi0) >> 1; if (gid[m] < g) lo0 = m + 1; else hi0 = m; }
  int lo1 = lo0, hi1 = kNodes;
  while (lo1 < hi1) { int m = (lo1 + hi1) >> 1; if (gid[m] < g + 1) lo1 = m + 1; else hi1 = m; }
  float rc = 1.0f / fmaxf((float)(lo1 - lo0), 1.0f);
  if (c < kClasses) {
    float acc = bp[c];
    for (int k = 0; k < kDhid; ++k)
      acc += gsum[g * kDhid + k] * rc * Wp[k * kClasses + c];
    out[g * kClasses + c] = acc;
  }
}

// ---------------------------------------------------------------------------
extern "C" void kernel_launch(void* const* d_in, const int* in_sizes, int n_in,
                              void* d_out, int out_size, void* d_ws, size_t ws_size,
                              hipStream_t stream) {
  const float* h  = (const float*)d_in[0];
  const float* Ws = (const float*)d_in[1];
  const float* Wn = (const float*)d_in[2];
  const float* b  = (const float*)d_in[3];
  const float* Wp = (const float*)d_in[4];
  const float* bp = (const float*)d_in[5];
  const int* src  = (const int*)d_in[6];
  const int* dst  = (const int*)d_in[7];
  const int* gid  = (const int*)d_in[8];
  float* out = (float*)d_out;

  char* ws = (char*)d_ws;
  const size_t a16Off  = 0;                       // 100096*256*2 = 51,249,152
  const size_t wtOff   = 51249152;                // 256*256*2    =    131,072
  const size_t csrOff  = 51380224;                // 1.6M*4       =  6,400,000
  const size_t rowOff  = 57780224;                // 100001*4     ->   400,016
  const size_t curOff  = 58180240;                // 100000*4     =    400,000
  const size_t gsumOff = 58580240;                // 64*256*4     =     65,536
  ushort* A16   = (ushort*)(ws + a16Off);
  ushort* Wt    = (ushort*)(ws + wtOff);
  int* csr      = (int*)(ws + csrOff);
  int* row      = (int*)(ws + rowOff);
  int* cursor   = (int*)(ws + curOff);
  float* gsum   = (float*)(ws + gsumOff);

  // zero row + cursor + gsum (contiguous)
  hipMemsetAsync(ws + rowOff, 0, (58580240 + 65536) - 57780224, stream);

  int eblk = (kEdges + 255) / 256;
  hipLaunchKernelGGL(count_deg, dim3(eblk), dim3(256), 0, stream, dst, row);
  hipLaunchKernelGGL(scan_offsets, dim3(1), dim3(1024), 0, stream, row);
  hipLaunchKernelGGL(fill_csr, dim3(eblk), dim3(256), 0, stream, src, dst, row, cursor, csr);

  hipLaunchKernelGGL(cvt_h, dim3((kNodesPad * 32 + 255) / 256), dim3(256), 0, stream, h, A16);
  hipLaunchKernelGGL(cvt_w, dim3((kK * kDhid + 255) / 256), dim3(256), 0, stream, Ws, Wn, Wt);
  hipLaunchKernelGGL(aggregate, dim3((kNodesPad + 3) / 4), dim3(256), 0, stream, A16, row, csr);

  hipLaunchKernelGGL(gemm_pool, dim3((kNodesPad / 128) * 2), dim3(256), 0, stream,
                     A16, Wt, b, gid, gsum);
  hipLaunchKernelGGL(head_kernel, dim3(kGraphs), dim3(64), 0, stream,
                     gsum, Wp, bp, gid, out);
}

// Round 4
// 339.215 us; speedup vs baseline: 26.5063x; 1.7374x over previous
//
#include <hip/hip_runtime.h>
#include <stdint.h>

constexpr int kNodes    = 100000;
constexpr int kNodesPad = 100096;   // 782 * 128
constexpr int kEdges    = 1600000;
constexpr int kDin      = 128;
constexpr int kK        = 256;      // concat K = [h | h_neigh]
constexpr int kDhid     = 256;
constexpr int kClasses  = 40;
constexpr int kGraphs   = 64;
constexpr int kScanBlocks = (kNodes + 1 + 255) / 256;   // 391

typedef __attribute__((ext_vector_type(8))) short bf8_t;   // 8 x bf16 (4 VGPR)
typedef __attribute__((ext_vector_type(4))) float f4_t;    // mfma C/D

__device__ inline ushort f2bf(float f) {
  uint32_t u = __float_as_uint(f);
  u += 0x7fff + ((u >> 16) & 1);          // RNE
  return (ushort)(u >> 16);
}
__device__ inline float bf2f(ushort b) { return __uint_as_float(((uint32_t)b) << 16); }

// ---------------------------------------------------------------------------
// CSR build: count -> hierarchical scan (3 kernels) -> fill
// ---------------------------------------------------------------------------
__global__ void count_deg(const int* __restrict__ dst, int* __restrict__ row) {
  int e = blockIdx.x * blockDim.x + threadIdx.x;
  if (e < kEdges) atomicAdd(&row[dst[e] + 1], 1);
}

// phase 1: per-256-block inclusive scan (in place) + block total -> bsum[b]
__global__ void scan_part(int* __restrict__ row, int* __restrict__ bsum) {
  __shared__ int s[256];
  int t = threadIdx.x;
  int i = blockIdx.x * 256 + t;
  int v = (i <= kNodes) ? row[i] : 0;
  s[t] = v;
  __syncthreads();
#pragma unroll
  for (int off = 1; off < 256; off <<= 1) {
    int u = (t >= off) ? s[t - off] : 0;
    __syncthreads();
    s[t] += u;
    __syncthreads();
  }
  if (i <= kNodes) row[i] = s[t];
  if (t == 255) bsum[blockIdx.x] = s[255];
}

// phase 2: single small block scans the 391 block sums (inclusive, in place)
__global__ void scan_bsum(int* __restrict__ bsum) {
  __shared__ int s[512];
  int t = threadIdx.x;
  s[t] = (t < kScanBlocks) ? bsum[t] : 0;
  __syncthreads();
#pragma unroll
  for (int off = 1; off < 512; off <<= 1) {
    int u = (t >= off) ? s[t - off] : 0;
    __syncthreads();
    s[t] += u;
    __syncthreads();
  }
  if (t < kScanBlocks) bsum[t] = s[t];
}

// phase 3: add previous blocks' totals
__global__ void scan_add(int* __restrict__ row, const int* __restrict__ bsum) {
  int b = blockIdx.x + 1;                  // blocks 1..390
  int i = b * 256 + threadIdx.x;
  if (i <= kNodes) row[i] += bsum[b - 1];
}

__global__ void fill_csr(const int* __restrict__ src, const int* __restrict__ dst,
                         const int* __restrict__ row, int* __restrict__ cursor,
                         int* __restrict__ csr) {
  int e = blockIdx.x * blockDim.x + threadIdx.x;
  if (e >= kEdges) return;
  int d = dst[e];
  int pos = atomicAdd(&cursor[d], 1);
  csr[row[d] + pos] = src[e];
}

// ---------------------------------------------------------------------------
// cvt_h: h fp32 -> A16[n][0..127] bf16 (zeros for padded rows)
// ---------------------------------------------------------------------------
__global__ void cvt_h(const float* __restrict__ h, ushort* __restrict__ A16) {
  int t = blockIdx.x * blockDim.x + threadIdx.x;
  if (t >= kNodesPad * 32) return;
  int n = t >> 5;
  int c4 = (t & 31) * 4;
  float4 v = make_float4(0.f, 0.f, 0.f, 0.f);
  if (n < kNodes) v = *reinterpret_cast<const float4*>(h + (size_t)n * kDin + c4);
  ushort4 o;
  o.x = f2bf(v.x); o.y = f2bf(v.y); o.z = f2bf(v.z); o.w = f2bf(v.w);
  *reinterpret_cast<ushort4*>(A16 + (size_t)n * kK + c4) = o;
}

// ---------------------------------------------------------------------------
// cvt_w: Wt[j][k] = bf16( k<128 ? Ws[k][j] : Wn[k-128][j] )   (transposed)
// ---------------------------------------------------------------------------
__global__ void cvt_w(const float* __restrict__ Ws, const float* __restrict__ Wn,
                      ushort* __restrict__ Wt) {
  int t = blockIdx.x * blockDim.x + threadIdx.x;
  if (t >= kK * kDhid) return;
  int j = t & 255;
  int k = t >> 8;
  float v = (k < 128) ? Ws[(size_t)k * kDhid + j] : Wn[(size_t)(k - 128) * kDhid + j];
  Wt[(size_t)j * kK + k] = f2bf(v);
}

// ---------------------------------------------------------------------------
// aggregate: A16[n][128..255] = bf16( mean over in-neighbors of A16[s][0..127] )
// one wave per node; lane owns 2 bf16 (one dword). 4-way unrolled gathers.
// ---------------------------------------------------------------------------
__global__ void aggregate(ushort* __restrict__ A16, const int* __restrict__ row,
                          const int* __restrict__ csr) {
  int n = blockIdx.x * 4 + (threadIdx.x >> 6);
  if (n >= kNodesPad) return;
  int lane = threadIdx.x & 63;
  uint32_t* outp = (uint32_t*)(A16 + (size_t)n * kK + kDin) + lane;
  if (n >= kNodes) { *outp = 0u; return; }
  int s0 = row[n], s1 = row[n + 1];
  float ax = 0.f, ay = 0.f;
  int i = s0;
  for (; i + 4 <= s1; i += 4) {
    int sa = csr[i], sb = csr[i + 1], sc = csr[i + 2], sd = csr[i + 3];
    uint32_t va = *((const uint32_t*)(A16 + (size_t)sa * kK) + lane);
    uint32_t vb = *((const uint32_t*)(A16 + (size_t)sb * kK) + lane);
    uint32_t vc = *((const uint32_t*)(A16 + (size_t)sc * kK) + lane);
    uint32_t vd = *((const uint32_t*)(A16 + (size_t)sd * kK) + lane);
    ax += bf2f((ushort)(va & 0xffffu)) + bf2f((ushort)(vb & 0xffffu)) +
          bf2f((ushort)(vc & 0xffffu)) + bf2f((ushort)(vd & 0xffffu));
    ay += bf2f((ushort)(va >> 16)) + bf2f((ushort)(vb >> 16)) +
          bf2f((ushort)(vc >> 16)) + bf2f((ushort)(vd >> 16));
  }
  for (; i < s1; ++i) {
    int s = csr[i];
    uint32_t v = *((const uint32_t*)(A16 + (size_t)s * kK) + lane);
    ax += bf2f((ushort)(v & 0xffffu));
    ay += bf2f((ushort)(v >> 16));
  }
  float rd = 1.f / fmaxf((float)(s1 - s0), 1.f);
  *outp = (uint32_t)f2bf(ax * rd) | ((uint32_t)f2bf(ay * rd) << 16);
}

// ---------------------------------------------------------------------------
// gemm_pool: hid = relu(A16 @ Wt^T + b) fused with per-graph pooling.
// 128x128 tile, 4 waves, mfma_f32_16x16x32_bf16, K=256 in two 128-steps.
// LDS tiles [128 rows][128 k] bf16, XOR-swizzled (T2) via pre-swizzled
// global source (global_load_lds writes linearly; rule #21).
// ---------------------------------------------------------------------------
__global__ __launch_bounds__(256, 2)
void gemm_pool(const ushort* __restrict__ A16, const ushort* __restrict__ Wt,
               const float* __restrict__ bias, const int* __restrict__ gid,
               float* __restrict__ gsum) {
  __shared__ union {
    struct { ushort A[128 * 128]; ushort B[128 * 128]; } st;  // 32KB + 32KB
    float hid[128][128];                                      // 64KB (reused)
  } sm;
  const int tid  = threadIdx.x;
  const int lane = tid & 63;
  const int wave = tid >> 6;
  const int wr = wave >> 1, wc = wave & 1;
  const int cb = blockIdx.x & 1;
  const int rb = blockIdx.x >> 1;
  const int nbase = rb * 128;
  const int jbase = cb * 128;
  const int lhi = lane >> 4;   // 0..3
  const int llo = lane & 15;

  f4_t acc[4][4];
#pragma unroll
  for (int i = 0; i < 4; ++i)
#pragma unroll
    for (int j = 0; j < 4; ++j) acc[i][j] = (f4_t)0.f;

  for (int k0 = 0; k0 < 2; ++k0) {   // K offset = k0*128
    // ---- stage A and B tiles: each wave 8 segments x 1KB each ----
#pragma unroll
    for (int s = 0; s < 8; ++s) {
      int r = wave * 32 + s * 4 + lhi;                 // tile row this lane feeds
      int swz = (llo * 16) ^ ((r & 7) << 4);           // inverse-swizzled source col
      size_t ga = (size_t)(nbase + r) * 512 + (size_t)k0 * 256 + swz;
      size_t gb = (size_t)(jbase + r) * 512 + (size_t)k0 * 256 + swz;
      uint32_t ldsOff = (uint32_t)(wave * 32 + s * 4) * 256;  // bytes, wave-uniform
      __builtin_amdgcn_global_load_lds(
          (const __attribute__((address_space(1))) uint32_t*)((const char*)A16 + ga),
          (__attribute__((address_space(3))) uint32_t*)((char*)sm.st.A + ldsOff),
          16, 0, 0);
      __builtin_amdgcn_global_load_lds(
          (const __attribute__((address_space(1))) uint32_t*)((const char*)Wt + gb),
          (__attribute__((address_space(3))) uint32_t*)((char*)sm.st.B + ldsOff),
          16, 0, 0);
    }
    __syncthreads();
    // ---- compute: 4 k-slices of 32 ----
#pragma unroll
    for (int kh = 0; kh < 4; ++kh) {
      const int kb = kh * 64 + lhi * 16;               // byte offset of this lane's k-octet
      bf8_t av[4], bv[4];
#pragma unroll
      for (int mf = 0; mf < 4; ++mf) {
        int m = wr * 64 + mf * 16 + llo;
        av[mf] = *reinterpret_cast<const bf8_t*>(
            (const char*)sm.st.A + m * 256 + (kb ^ ((m & 7) << 4)));
      }
#pragma unroll
      for (int nf = 0; nf < 4; ++nf) {
        int j = wc * 64 + nf * 16 + llo;
        bv[nf] = *reinterpret_cast<const bf8_t*>(
            (const char*)sm.st.B + j * 256 + (kb ^ ((j & 7) << 4)));
      }
#pragma unroll
      for (int mf = 0; mf < 4; ++mf)
#pragma unroll
        for (int nf = 0; nf < 4; ++nf)
          acc[mf][nf] = __builtin_amdgcn_mfma_f32_16x16x32_bf16(av[mf], bv[nf], acc[mf][nf], 0, 0, 0);
    }
    __syncthreads();
  }

  // ---- epilogue: bias + relu into LDS hid tile ----
  float bvv[4];
#pragma unroll
  for (int nf = 0; nf < 4; ++nf) bvv[nf] = bias[jbase + wc * 64 + nf * 16 + llo];
#pragma unroll
  for (int mf = 0; mf < 4; ++mf)
#pragma unroll
    for (int nf = 0; nf < 4; ++nf) {
      int col = wc * 64 + nf * 16 + llo;
#pragma unroll
      for (int q = 0; q < 4; ++q) {
        int rowi = wr * 64 + mf * 16 + lhi * 4 + q;    // C/D: col=lane&15, row=(lane>>4)*4+q
        sm.hid[rowi][col] = fmaxf(acc[mf][nf][q] + bvv[nf], 0.f);
      }
    }
  __syncthreads();

  // ---- per-graph pooling (gid sorted) ----
  int lastnode = min(nbase + 128, kNodes) - 1;
  int g0 = gid[nbase];
  int g1 = gid[lastnode];
  int c = tid & 127;
  int half = tid >> 7;
  for (int g = g0; g <= g1; ++g) {
    float sacc = 0.f;
    for (int r = half * 64; r < half * 64 + 64; ++r) {
      int node = nbase + r;
      if (node < kNodes && gid[node] == g) sacc += sm.hid[r][c];
    }
    if (sacc != 0.f) atomicAdd(&gsum[g * kDhid + jbase + c], sacc);
  }
}

// ---------------------------------------------------------------------------
// head: out[g] = (gsum[g]/cnt[g]) @ Wp + bp, cnt via binary search on gid.
// ---------------------------------------------------------------------------
__global__ void head_kernel(const float* __restrict__ gsum,
                            const float* __restrict__ Wp,
                            const float* __restrict__ bp,
                            const int* __restrict__ gid,
                            float* __restrict__ out) {
  int g = blockIdx.x;
  int c = threadIdx.x;
  int lo0 = 0, hi0 = kNodes;
  while (lo0 < hi0) { int m = (lo0 + hi0) >> 1; if (gid[m] < g) lo0 = m + 1; else hi0 = m; }
  int lo1 = lo0, hi1 = kNodes;
  while (lo1 < hi1) { int m = (lo1 + hi1) >> 1; if (gid[m] < g + 1) lo1 = m + 1; else hi1 = m; }
  float rc = 1.0f / fmaxf((float)(lo1 - lo0), 1.0f);
  if (c < kClasses) {
    float acc = bp[c];
    for (int k = 0; k < kDhid; ++k)
      acc += gsum[g * kDhid + k] * rc * Wp[k * kClasses + c];
    out[g * kClasses + c] = acc;
  }
}

// ---------------------------------------------------------------------------
extern "C" void kernel_launch(void* const* d_in, const int* in_sizes, int n_in,
                              void* d_out, int out_size, void* d_ws, size_t ws_size,
                              hipStream_t stream) {
  const float* h  = (const float*)d_in[0];
  const float* Ws = (const float*)d_in[1];
  const float* Wn = (const float*)d_in[2];
  const float* b  = (const float*)d_in[3];
  const float* Wp = (const float*)d_in[4];
  const float* bp = (const float*)d_in[5];
  const int* src  = (const int*)d_in[6];
  const int* dst  = (const int*)d_in[7];
  const int* gid  = (const int*)d_in[8];
  float* out = (float*)d_out;

  char* ws = (char*)d_ws;
  const size_t a16Off  = 0;                       // 100096*256*2 = 51,249,152
  const size_t wtOff   = 51249152;                // 256*256*2    =    131,072
  const size_t csrOff  = 51380224;                // 1.6M*4       =  6,400,000
  const size_t rowOff  = 57780224;                // 100001*4     ->   400,016
  const size_t curOff  = 58180240;                // 100000*4     =    400,000
  const size_t gsumOff = 58580240;                // 64*256*4     =     65,536
  const size_t bsumOff = 58645776;                // 391*4        =      1,564
  ushort* A16   = (ushort*)(ws + a16Off);
  ushort* Wt    = (ushort*)(ws + wtOff);
  int* csr      = (int*)(ws + csrOff);
  int* row      = (int*)(ws + rowOff);
  int* cursor   = (int*)(ws + curOff);
  float* gsum   = (float*)(ws + gsumOff);
  int* bsum     = (int*)(ws + bsumOff);

  // zero row + cursor + gsum (contiguous)
  hipMemsetAsync(ws + rowOff, 0, (58580240 + 65536) - 57780224, stream);

  int eblk = (kEdges + 255) / 256;
  hipLaunchKernelGGL(count_deg, dim3(eblk), dim3(256), 0, stream, dst, row);
  hipLaunchKernelGGL(scan_part, dim3(kScanBlocks), dim3(256), 0, stream, row, bsum);
  hipLaunchKernelGGL(scan_bsum, dim3(1), dim3(512), 0, stream, bsum);
  hipLaunchKernelGGL(scan_add, dim3(kScanBlocks - 1), dim3(256), 0, stream, row, bsum);
  hipLaunchKernelGGL(fill_csr, dim3(eblk), dim3(256), 0, stream, src, dst, row, cursor, csr);

  hipLaunchKernelGGL(cvt_h, dim3((kNodesPad * 32 + 255) / 256), dim3(256), 0, stream, h, A16);
  hipLaunchKernelGGL(cvt_w, dim3((kK * kDhid + 255) / 256), dim3(256), 0, stream, Ws, Wn, Wt);
  hipLaunchKernelGGL(aggregate, dim3((kNodesPad + 3) / 4), dim3(256), 0, stream, A16, row, csr);

  hipLaunchKernelGGL(gemm_pool, dim3((kNodesPad / 128) * 2), dim3(256), 0, stream,
                     A16, Wt, b, gid, gsum);
  hipLaunchKernelGGL(head_kernel, dim3(kGraphs), dim3(64), 0, stream,
                     gsum, Wp, bp, gid, out);
}

// Round 5
// 238.260 us; speedup vs baseline: 37.7375x; 1.4237x over previous
//
#include <hip/hip_runtime.h>
#include <stdint.h>

constexpr int kNodes    = 100000;
constexpr int kNodesPad = 100096;   // 782 * 128
constexpr int kEdges    = 1600000;
constexpr int kDin      = 128;
constexpr int kK        = 256;      // concat K = [h | h_neigh]
constexpr int kDhid     = 256;
constexpr int kClasses  = 40;
constexpr int kGraphs   = 64;

constexpr int kBktShift = 9;                       // 512 nodes per bucket
constexpr int NB = (kNodes + 511) >> 9;            // 196 buckets
constexpr int kChunk = 6250;                       // edges per block in count/scatter
constexpr int kEBlocks = (kEdges + kChunk - 1) / kChunk;  // 256

typedef __attribute__((ext_vector_type(8))) short bf8_t;   // 8 x bf16 (4 VGPR)
typedef __attribute__((ext_vector_type(4))) float f4_t;    // mfma C/D

__device__ inline ushort f2bf(float f) {
  uint32_t u = __float_as_uint(f);
  u += 0x7fff + ((u >> 16) & 1);          // RNE
  return (ushort)(u >> 16);
}
__device__ inline float bf2f(ushort b) { return __uint_as_float(((uint32_t)b) << 16); }

// ---------------------------------------------------------------------------
// Bucketed CSR build: count -> starts -> scatter pairs -> per-bucket fill
// ---------------------------------------------------------------------------
__global__ void bucket_count(const int* __restrict__ dst, int* __restrict__ bktCursor) {
  __shared__ int hist[NB];
  for (int i = threadIdx.x; i < NB; i += 256) hist[i] = 0;
  __syncthreads();
  int e0 = blockIdx.x * kChunk;
  int e1 = min(e0 + kChunk, kEdges);
  for (int e = e0 + threadIdx.x; e < e1; e += 256)
    atomicAdd(&hist[dst[e] >> kBktShift], 1);
  __syncthreads();
  for (int i = threadIdx.x; i < NB; i += 256)
    if (hist[i]) atomicAdd(&bktCursor[i], hist[i]);
}

__global__ void bucket_starts(int* __restrict__ bktCursor, int* __restrict__ bktStart) {
  __shared__ int s[256];
  int t = threadIdx.x;
  int v = (t < NB) ? bktCursor[t] : 0;
  s[t] = v;
  __syncthreads();
#pragma unroll
  for (int off = 1; off < 256; off <<= 1) {
    int u = (t >= off) ? s[t - off] : 0;
    __syncthreads();
    s[t] += u;
    __syncthreads();
  }
  int excl = s[t] - v;
  if (t < NB) { bktStart[t] = excl; bktCursor[t] = excl; }
  if (t == NB - 1) bktStart[NB] = s[t];
}

__global__ void bucket_scatter(const int* __restrict__ src, const int* __restrict__ dst,
                               int* __restrict__ bktCursor, int2* __restrict__ pairs) {
  __shared__ int hist[NB], base[NB], cur[NB];
  for (int i = threadIdx.x; i < NB; i += 256) { hist[i] = 0; cur[i] = 0; }
  __syncthreads();
  int e0 = blockIdx.x * kChunk;
  int e1 = min(e0 + kChunk, kEdges);
  for (int e = e0 + threadIdx.x; e < e1; e += 256)
    atomicAdd(&hist[dst[e] >> kBktShift], 1);
  __syncthreads();
  for (int i = threadIdx.x; i < NB; i += 256)
    base[i] = hist[i] ? atomicAdd(&bktCursor[i], hist[i]) : 0;
  __syncthreads();
  for (int e = e0 + threadIdx.x; e < e1; e += 256) {
    int d = dst[e];
    int b = d >> kBktShift;
    int p = atomicAdd(&cur[b], 1);
    pairs[base[b] + p] = make_int2(src[e], d);
  }
}

__global__ void bucket_fill(const int2* __restrict__ pairs, const int* __restrict__ bktStart,
                            int* __restrict__ row, int* __restrict__ csr) {
  __shared__ int deg[512], scn[512], cur[512];
  int b = blockIdx.x;
  int t = threadIdx.x;
  int e0 = bktStart[b], e1 = bktStart[b + 1];
  int nb0 = b << kBktShift;
  deg[t] = 0;
  __syncthreads();
  for (int e = e0 + t; e < e1; e += 512)
    atomicAdd(&deg[pairs[e].y - nb0], 1);
  __syncthreads();
  int d = deg[t];
  scn[t] = d;
  __syncthreads();
#pragma unroll
  for (int off = 1; off < 512; off <<= 1) {
    int u = (t >= off) ? scn[t - off] : 0;
    __syncthreads();
    scn[t] += u;
    __syncthreads();
  }
  int excl = scn[t] - d;
  cur[t] = excl;
  int n = nb0 + t;
  if (n <= kNodes) row[n] = e0 + excl;
  __syncthreads();
  for (int e = e0 + t; e < e1; e += 512) {
    int2 pr = pairs[e];
    int p = atomicAdd(&cur[pr.y - nb0], 1);
    csr[e0 + p] = pr.x;
  }
}

// ---------------------------------------------------------------------------
// cvt_h: h fp32 -> A16[n][0..127] bf16 (zeros for padded rows)
// ---------------------------------------------------------------------------
__global__ void cvt_h(const float* __restrict__ h, ushort* __restrict__ A16) {
  int t = blockIdx.x * blockDim.x + threadIdx.x;
  if (t >= kNodesPad * 32) return;
  int n = t >> 5;
  int c4 = (t & 31) * 4;
  float4 v = make_float4(0.f, 0.f, 0.f, 0.f);
  if (n < kNodes) v = *reinterpret_cast<const float4*>(h + (size_t)n * kDin + c4);
  ushort4 o;
  o.x = f2bf(v.x); o.y = f2bf(v.y); o.z = f2bf(v.z); o.w = f2bf(v.w);
  *reinterpret_cast<ushort4*>(A16 + (size_t)n * kK + c4) = o;
}

// ---------------------------------------------------------------------------
// cvt_w: Wt[j][k] = bf16( k<128 ? Ws[k][j] : Wn[k-128][j] )   (transposed)
// ---------------------------------------------------------------------------
__global__ void cvt_w(const float* __restrict__ Ws, const float* __restrict__ Wn,
                      ushort* __restrict__ Wt) {
  int t = blockIdx.x * blockDim.x + threadIdx.x;
  if (t >= kK * kDhid) return;
  int j = t & 255;
  int k = t >> 8;
  float v = (k < 128) ? Ws[(size_t)k * kDhid + j] : Wn[(size_t)(k - 128) * kDhid + j];
  Wt[(size_t)j * kK + k] = f2bf(v);
}

// ---------------------------------------------------------------------------
// aggregate: A16[n][128..255] = bf16( mean over in-neighbors of A16[s][0..127] )
// one wave per node; lane owns 2 bf16 (one dword). 8-way unrolled gathers.
// ---------------------------------------------------------------------------
__global__ void aggregate(ushort* __restrict__ A16, const int* __restrict__ row,
                          const int* __restrict__ csr) {
  int n = blockIdx.x * 4 + (threadIdx.x >> 6);
  if (n >= kNodesPad) return;
  int lane = threadIdx.x & 63;
  uint32_t* outp = (uint32_t*)(A16 + (size_t)n * kK + kDin) + lane;
  if (n >= kNodes) { *outp = 0u; return; }
  int s0 = row[n], s1 = row[n + 1];
  float ax = 0.f, ay = 0.f;
  int i = s0;
  for (; i + 8 <= s1; i += 8) {
    int sidx[8];
#pragma unroll
    for (int u = 0; u < 8; ++u) sidx[u] = csr[i + u];
    uint32_t v[8];
#pragma unroll
    for (int u = 0; u < 8; ++u)
      v[u] = *((const uint32_t*)(A16 + (size_t)sidx[u] * kK) + lane);
#pragma unroll
    for (int u = 0; u < 8; ++u) {
      ax += bf2f((ushort)(v[u] & 0xffffu));
      ay += bf2f((ushort)(v[u] >> 16));
    }
  }
  for (; i < s1; ++i) {
    int s = csr[i];
    uint32_t v = *((const uint32_t*)(A16 + (size_t)s * kK) + lane);
    ax += bf2f((ushort)(v & 0xffffu));
    ay += bf2f((ushort)(v >> 16));
  }
  float rd = 1.f / fmaxf((float)(s1 - s0), 1.f);
  *outp = (uint32_t)f2bf(ax * rd) | ((uint32_t)f2bf(ay * rd) << 16);
}

// ---------------------------------------------------------------------------
// gemm_pool: hid = relu(A16 @ Wt^T + b) fused with per-graph pooling.
// 128x128 tile, 4 waves, mfma_f32_16x16x32_bf16, K=256 in two 128-steps.
// LDS tiles XOR-swizzled (T2) via pre-swizzled global source (rule #21).
// ---------------------------------------------------------------------------
__global__ __launch_bounds__(256, 2)
void gemm_pool(const ushort* __restrict__ A16, const ushort* __restrict__ Wt,
               const float* __restrict__ bias, const int* __restrict__ gid,
               float* __restrict__ gsum) {
  __shared__ union {
    struct { ushort A[128 * 128]; ushort B[128 * 128]; } st;  // 32KB + 32KB
    float hid[128][128];                                      // 64KB (reused)
  } sm;
  const int tid  = threadIdx.x;
  const int lane = tid & 63;
  const int wave = tid >> 6;
  const int wr = wave >> 1, wc = wave & 1;
  const int cb = blockIdx.x & 1;
  const int rb = blockIdx.x >> 1;
  const int nbase = rb * 128;
  const int jbase = cb * 128;
  const int lhi = lane >> 4;   // 0..3
  const int llo = lane & 15;

  f4_t acc[4][4];
#pragma unroll
  for (int i = 0; i < 4; ++i)
#pragma unroll
    for (int j = 0; j < 4; ++j) acc[i][j] = (f4_t)0.f;

  for (int k0 = 0; k0 < 2; ++k0) {   // K offset = k0*128
#pragma unroll
    for (int s = 0; s < 8; ++s) {
      int r = wave * 32 + s * 4 + lhi;
      int swz = (llo * 16) ^ ((r & 7) << 4);
      size_t ga = (size_t)(nbase + r) * 512 + (size_t)k0 * 256 + swz;
      size_t gb = (size_t)(jbase + r) * 512 + (size_t)k0 * 256 + swz;
      uint32_t ldsOff = (uint32_t)(wave * 32 + s * 4) * 256;
      __builtin_amdgcn_global_load_lds(
          (const __attribute__((address_space(1))) uint32_t*)((const char*)A16 + ga),
          (__attribute__((address_space(3))) uint32_t*)((char*)sm.st.A + ldsOff),
          16, 0, 0);
      __builtin_amdgcn_global_load_lds(
          (const __attribute__((address_space(1))) uint32_t*)((const char*)Wt + gb),
          (__attribute__((address_space(3))) uint32_t*)((char*)sm.st.B + ldsOff),
          16, 0, 0);
    }
    __syncthreads();
#pragma unroll
    for (int kh = 0; kh < 4; ++kh) {
      const int kb = kh * 64 + lhi * 16;
      bf8_t av[4], bv[4];
#pragma unroll
      for (int mf = 0; mf < 4; ++mf) {
        int m = wr * 64 + mf * 16 + llo;
        av[mf] = *reinterpret_cast<const bf8_t*>(
            (const char*)sm.st.A + m * 256 + (kb ^ ((m & 7) << 4)));
      }
#pragma unroll
      for (int nf = 0; nf < 4; ++nf) {
        int j = wc * 64 + nf * 16 + llo;
        bv[nf] = *reinterpret_cast<const bf8_t*>(
            (const char*)sm.st.B + j * 256 + (kb ^ ((j & 7) << 4)));
      }
#pragma unroll
      for (int mf = 0; mf < 4; ++mf)
#pragma unroll
        for (int nf = 0; nf < 4; ++nf)
          acc[mf][nf] = __builtin_amdgcn_mfma_f32_16x16x32_bf16(av[mf], bv[nf], acc[mf][nf], 0, 0, 0);
    }
    __syncthreads();
  }

  float bvv[4];
#pragma unroll
  for (int nf = 0; nf < 4; ++nf) bvv[nf] = bias[jbase + wc * 64 + nf * 16 + llo];
#pragma unroll
  for (int mf = 0; mf < 4; ++mf)
#pragma unroll
    for (int nf = 0; nf < 4; ++nf) {
      int col = wc * 64 + nf * 16 + llo;
#pragma unroll
      for (int q = 0; q < 4; ++q) {
        int rowi = wr * 64 + mf * 16 + lhi * 4 + q;
        sm.hid[rowi][col] = fmaxf(acc[mf][nf][q] + bvv[nf], 0.f);
      }
    }
  __syncthreads();

  int lastnode = min(nbase + 128, kNodes) - 1;
  int g0 = gid[nbase];
  int g1 = gid[lastnode];
  int c = tid & 127;
  int half = tid >> 7;
  for (int g = g0; g <= g1; ++g) {
    float sacc = 0.f;
    for (int r = half * 64; r < half * 64 + 64; ++r) {
      int node = nbase + r;
      if (node < kNodes && gid[node] == g) sacc += sm.hid[r][c];
    }
    if (sacc != 0.f) atomicAdd(&gsum[g * kDhid + jbase + c], sacc);
  }
}

// ---------------------------------------------------------------------------
// head: out[g] = (gsum[g]/cnt[g]) @ Wp + bp, cnt via binary search on gid.
// ---------------------------------------------------------------------------
__global__ void head_kernel(const float* __restrict__ gsum,
                            const float* __restrict__ Wp,
                            const float* __restrict__ bp,
                            const int* __restrict__ gid,
                            float* __restrict__ out) {
  int g = blockIdx.x;
  int c = threadIdx.x;
  int lo0 = 0, hi0 = kNodes;
  while (lo0 < hi0) { int m = (lo0 + hi0) >> 1; if (gid[m] < g) lo0 = m + 1; else hi0 = m; }
  int lo1 = lo0, hi1 = kNodes;
  while (lo1 < hi1) { int m = (lo1 + hi1) >> 1; if (gid[m] < g + 1) lo1 = m + 1; else hi1 = m; }
  float rc = 1.0f / fmaxf((float)(lo1 - lo0), 1.0f);
  if (c < kClasses) {
    float acc = bp[c];
    for (int k = 0; k < kDhid; ++k)
      acc += gsum[g * kDhid + k] * rc * Wp[k * kClasses + c];
    out[g * kClasses + c] = acc;
  }
}

// ---------------------------------------------------------------------------
extern "C" void kernel_launch(void* const* d_in, const int* in_sizes, int n_in,
                              void* d_out, int out_size, void* d_ws, size_t ws_size,
                              hipStream_t stream) {
  const float* h  = (const float*)d_in[0];
  const float* Ws = (const float*)d_in[1];
  const float* Wn = (const float*)d_in[2];
  const float* b  = (const float*)d_in[3];
  const float* Wp = (const float*)d_in[4];
  const float* bp = (const float*)d_in[5];
  const int* src  = (const int*)d_in[6];
  const int* dst  = (const int*)d_in[7];
  const int* gid  = (const int*)d_in[8];
  float* out = (float*)d_out;

  char* ws = (char*)d_ws;
  // pairs (12.8MB) aliases A16 (51.2MB): pairs dead before cvt_h runs.
  const size_t a16Off      = 0;             // 100096*256*2 = 51,249,152
  const size_t wtOff       = 51249152;      // 131,072
  const size_t csrOff      = 51380224;      // 6,400,000
  const size_t rowOff      = 57780224;      // 400,016 (100001*4 padded)
  const size_t gsumOff     = 58180240;      // 65,536
  const size_t bktStartOff = 58245776;      // 800 ((196+1)*4 padded)
  const size_t bktCurOff   = 58246576;      // 800
  ushort* A16   = (ushort*)(ws + a16Off);
  int2* pairs   = (int2*)(ws + a16Off);
  ushort* Wt    = (ushort*)(ws + wtOff);
  int* csr      = (int*)(ws + csrOff);
  int* row      = (int*)(ws + rowOff);
  float* gsum   = (float*)(ws + gsumOff);
  int* bktStart = (int*)(ws + bktStartOff);
  int* bktCur   = (int*)(ws + bktCurOff);

  // zero gsum + bktStart + bktCursor (contiguous 67,136 B)
  hipMemsetAsync(ws + gsumOff, 0, (58246576 + 800) - 58180240, stream);

  hipLaunchKernelGGL(bucket_count, dim3(kEBlocks), dim3(256), 0, stream, dst, bktCur);
  hipLaunchKernelGGL(bucket_starts, dim3(1), dim3(256), 0, stream, bktCur, bktStart);
  hipLaunchKernelGGL(bucket_scatter, dim3(kEBlocks), dim3(256), 0, stream, src, dst, bktCur, pairs);
  hipLaunchKernelGGL(bucket_fill, dim3(NB), dim3(512), 0, stream, pairs, bktStart, row, csr);

  hipLaunchKernelGGL(cvt_h, dim3((kNodesPad * 32 + 255) / 256), dim3(256), 0, stream, h, A16);
  hipLaunchKernelGGL(cvt_w, dim3((kK * kDhid + 255) / 256), dim3(256), 0, stream, Ws, Wn, Wt);
  hipLaunchKernelGGL(aggregate, dim3((kNodesPad + 3) / 4), dim3(256), 0, stream, A16, row, csr);

  hipLaunchKernelGGL(gemm_pool, dim3((kNodesPad / 128) * 2), dim3(256), 0, stream,
                     A16, Wt, b, gid, gsum);
  hipLaunchKernelGGL(head_kernel, dim3(kGraphs), dim3(64), 0, stream,
                     gsum, Wp, bp, gid, out);
}

// Round 6
// 205.359 us; speedup vs baseline: 43.7835x; 1.1602x over previous
//
#include <hip/hip_runtime.h>
#include <stdint.h>

constexpr int kNodes    = 100000;
constexpr int kEdges    = 1600000;
constexpr int kDin      = 128;
constexpr int kK        = 256;      // concat K = [h | h_neigh]
constexpr int kDhid     = 256;
constexpr int kClasses  = 40;
constexpr int kGraphs   = 64;

constexpr int kBktShift = 9;                       // 512 nodes per bucket
constexpr int NB = (kNodes + 511) >> 9;            // 196 buckets
constexpr int kChunk = 6250;                       // edges per block in count/scatter
constexpr int kEBlocks = (kEdges + kChunk - 1) / kChunk;  // 256

constexpr int kTPB = 5;                            // row-tiles (32 rows) per gemm block
constexpr int kTiles = kNodes / 32;                // 3125
constexpr int kGemmBlocks = kTiles / kTPB;         // 625

typedef __attribute__((ext_vector_type(8))) short bf8_t;   // 8 x bf16 (4 VGPR)
typedef __attribute__((ext_vector_type(4))) float f4_t;    // mfma C/D

__device__ inline ushort f2bf(float f) {
  uint32_t u = __float_as_uint(f);
  u += 0x7fff + ((u >> 16) & 1);          // RNE
  return (ushort)(u >> 16);
}
__device__ inline float bf2f(ushort b) { return __uint_as_float(((uint32_t)b) << 16); }

// ---------------------------------------------------------------------------
// Bucketed CSR build: count -> starts -> scatter pairs -> per-bucket fill
// ---------------------------------------------------------------------------
__global__ void bucket_count(const int* __restrict__ dst, int* __restrict__ bktCursor) {
  __shared__ int hist[NB];
  for (int i = threadIdx.x; i < NB; i += 256) hist[i] = 0;
  __syncthreads();
  int e0 = blockIdx.x * kChunk;
  int e1 = min(e0 + kChunk, kEdges);
  for (int e = e0 + threadIdx.x; e < e1; e += 256)
    atomicAdd(&hist[dst[e] >> kBktShift], 1);
  __syncthreads();
  for (int i = threadIdx.x; i < NB; i += 256)
    if (hist[i]) atomicAdd(&bktCursor[i], hist[i]);
}

__global__ void bucket_starts(int* __restrict__ bktCursor, int* __restrict__ bktStart) {
  __shared__ int s[256];
  int t = threadIdx.x;
  int v = (t < NB) ? bktCursor[t] : 0;
  s[t] = v;
  __syncthreads();
#pragma unroll
  for (int off = 1; off < 256; off <<= 1) {
    int u = (t >= off) ? s[t - off] : 0;
    __syncthreads();
    s[t] += u;
    __syncthreads();
  }
  int excl = s[t] - v;
  if (t < NB) { bktStart[t] = excl; bktCursor[t] = excl; }
  if (t == NB - 1) bktStart[NB] = s[t];
}

__global__ void bucket_scatter(const int* __restrict__ src, const int* __restrict__ dst,
                               int* __restrict__ bktCursor, int2* __restrict__ pairs) {
  __shared__ int hist[NB], base[NB], cur[NB];
  for (int i = threadIdx.x; i < NB; i += 256) { hist[i] = 0; cur[i] = 0; }
  __syncthreads();
  int e0 = blockIdx.x * kChunk;
  int e1 = min(e0 + kChunk, kEdges);
  for (int e = e0 + threadIdx.x; e < e1; e += 256)
    atomicAdd(&hist[dst[e] >> kBktShift], 1);
  __syncthreads();
  for (int i = threadIdx.x; i < NB; i += 256)
    base[i] = hist[i] ? atomicAdd(&bktCursor[i], hist[i]) : 0;
  __syncthreads();
  for (int e = e0 + threadIdx.x; e < e1; e += 256) {
    int d = dst[e];
    int b = d >> kBktShift;
    int p = atomicAdd(&cur[b], 1);
    pairs[base[b] + p] = make_int2(src[e], d);
  }
}

__global__ void bucket_fill(const int2* __restrict__ pairs, const int* __restrict__ bktStart,
                            int* __restrict__ row, int* __restrict__ csr) {
  __shared__ int deg[512], scn[512], cur[512];
  int b = blockIdx.x;
  int t = threadIdx.x;
  int e0 = bktStart[b], e1 = bktStart[b + 1];
  int nb0 = b << kBktShift;
  deg[t] = 0;
  __syncthreads();
  for (int e = e0 + t; e < e1; e += 512)
    atomicAdd(&deg[pairs[e].y - nb0], 1);
  __syncthreads();
  int d = deg[t];
  scn[t] = d;
  __syncthreads();
#pragma unroll
  for (int off = 1; off < 512; off <<= 1) {
    int u = (t >= off) ? scn[t - off] : 0;
    __syncthreads();
    scn[t] += u;
    __syncthreads();
  }
  int excl = scn[t] - d;
  cur[t] = excl;
  int n = nb0 + t;
  if (n <= kNodes) row[n] = e0 + excl;
  __syncthreads();
  for (int e = e0 + t; e < e1; e += 512) {
    int2 pr = pairs[e];
    int p = atomicAdd(&cur[pr.y - nb0], 1);
    csr[e0 + p] = pr.x;
  }
}

// ---------------------------------------------------------------------------
// cvt_h: h fp32 -> A16[n][0..127] bf16
// ---------------------------------------------------------------------------
__global__ void cvt_h(const float* __restrict__ h, ushort* __restrict__ A16) {
  int t = blockIdx.x * blockDim.x + threadIdx.x;
  if (t >= kNodes * 32) return;
  int n = t >> 5;
  int c4 = (t & 31) * 4;
  float4 v = *reinterpret_cast<const float4*>(h + (size_t)n * kDin + c4);
  ushort4 o;
  o.x = f2bf(v.x); o.y = f2bf(v.y); o.z = f2bf(v.z); o.w = f2bf(v.w);
  *reinterpret_cast<ushort4*>(A16 + (size_t)n * kK + c4) = o;
}

// ---------------------------------------------------------------------------
// cvt_w: Wt[j][k] = bf16( k<128 ? Ws[k][j] : Wn[k-128][j] )   (transposed)
// ---------------------------------------------------------------------------
__global__ void cvt_w(const float* __restrict__ Ws, const float* __restrict__ Wn,
                      ushort* __restrict__ Wt) {
  int t = blockIdx.x * blockDim.x + threadIdx.x;
  if (t >= kK * kDhid) return;
  int j = t & 255;
  int k = t >> 8;
  float v = (k < 128) ? Ws[(size_t)k * kDhid + j] : Wn[(size_t)(k - 128) * kDhid + j];
  Wt[(size_t)j * kK + k] = f2bf(v);
}

// ---------------------------------------------------------------------------
// aggregate: A16[n][128..255] = bf16( mean over in-neighbors of A16[s][0..127] )
// one wave per node; lane owns 2 bf16 (one dword). 8-way unrolled gathers.
// ---------------------------------------------------------------------------
__global__ void aggregate(ushort* __restrict__ A16, const int* __restrict__ row,
                          const int* __restrict__ csr) {
  int n = blockIdx.x * 4 + (threadIdx.x >> 6);
  if (n >= kNodes) return;
  int lane = threadIdx.x & 63;
  uint32_t* outp = (uint32_t*)(A16 + (size_t)n * kK + kDin) + lane;
  int s0 = row[n], s1 = row[n + 1];
  float ax = 0.f, ay = 0.f;
  int i = s0;
  for (; i + 8 <= s1; i += 8) {
    int sidx[8];
#pragma unroll
    for (int u = 0; u < 8; ++u) sidx[u] = csr[i + u];
    uint32_t v[8];
#pragma unroll
    for (int u = 0; u < 8; ++u)
      v[u] = *((const uint32_t*)(A16 + (size_t)sidx[u] * kK) + lane);
#pragma unroll
    for (int u = 0; u < 8; ++u) {
      ax += bf2f((ushort)(v[u] & 0xffffu));
      ay += bf2f((ushort)(v[u] >> 16));
    }
  }
  for (; i < s1; ++i) {
    int s = csr[i];
    uint32_t v = *((const uint32_t*)(A16 + (size_t)s * kK) + lane);
    ax += bf2f((ushort)(v & 0xffffu));
    ay += bf2f((ushort)(v >> 16));
  }
  float rd = 1.f / fmaxf((float)(s1 - s0), 1.f);
  *outp = (uint32_t)f2bf(ax * rd) | ((uint32_t)f2bf(ay * rd) << 16);
}

// ---------------------------------------------------------------------------
// gemm_pool v2: W-stationary streaming.  4 waves, wave owns 64 cols; B frags
// in registers (128 VGPR); 5 row-tiles of 32 rows streamed via double-buffered
// 16KB LDS A-tiles (global_load_lds, issue-before-compute).  Pooling in
// registers, flushed at graph boundaries (gid sorted) and block end.
// ---------------------------------------------------------------------------
__global__ __launch_bounds__(256, 2)
void gemm_pool(const ushort* __restrict__ A16, const ushort* __restrict__ Wt,
               const float* __restrict__ bias, const int* __restrict__ gid,
               float* __restrict__ gsum) {
  __shared__ ushort Abuf[2][32 * 256];   // 2 x 16 KB
  const int tid  = threadIdx.x;
  const int lane = tid & 63;
  const int wave = tid >> 6;             // col-slice: wave*64 .. +64
  const int lhi = lane >> 4;
  const int llo = lane & 15;

  // ---- B fragments (Wt rows j = wave*64+nf*16+llo, k-octet kk*4+lhi) ----
  bf8_t bfr[4][8];
#pragma unroll
  for (int nf = 0; nf < 4; ++nf) {
    const char* wrow = (const char*)Wt + (size_t)(wave * 64 + nf * 16 + llo) * 512 + lhi * 16;
#pragma unroll
    for (int kk = 0; kk < 8; ++kk)
      bfr[nf][kk] = *reinterpret_cast<const bf8_t*>(wrow + kk * 64);
  }
  float bv[4];
#pragma unroll
  for (int nf = 0; nf < 4; ++nf) bv[nf] = bias[wave * 64 + nf * 16 + llo];

  // ---- staging: LDS linear dest, inverse-swizzled global source (rule #21)
  auto stage = [&](int buf, int tile) {
#pragma unroll
    for (int i = 0; i < 4; ++i) {
      int r = i * 8 + (tid >> 5);
      int wb = (tid & 31) * 16;
      size_t gsrc = ((size_t)tile * 32 + r) * 512 + (size_t)(wb ^ ((r & 7) << 4));
      uint32_t ldst = (uint32_t)(i * 4096 + tid * 16);   // uniform base + lane*16
      __builtin_amdgcn_global_load_lds(
          (const __attribute__((address_space(1))) uint32_t*)((const char*)A16 + gsrc),
          (__attribute__((address_space(3))) uint32_t*)((char*)&Abuf[buf][0] + ldst),
          16, 0, 0);
    }
  };

  const int t0 = blockIdx.x * kTPB;
  stage(0, t0);
  __syncthreads();

  float pooled[4] = {0.f, 0.f, 0.f, 0.f};
  int cur_g = gid[t0 * 32];

  for (int ti = 0; ti < kTPB; ++ti) {
    int tile = t0 + ti;
    if (ti + 1 < kTPB) stage((ti + 1) & 1, tile + 1);   // prefetch next tile

    // ---- compute 32 rows x 256 cols, full K ----
    f4_t acc[2][4];
#pragma unroll
    for (int mf = 0; mf < 2; ++mf)
#pragma unroll
      for (int nf = 0; nf < 4; ++nf) acc[mf][nf] = (f4_t)0.f;
    const char* abase = (const char*)&Abuf[ti & 1][0];
    const int swz = (llo & 7) << 4;
#pragma unroll
    for (int kk = 0; kk < 8; ++kk) {
      int kb = kk * 64 + lhi * 16;
      bf8_t a0 = *reinterpret_cast<const bf8_t*>(abase + llo * 512 + (kb ^ swz));
      bf8_t a1 = *reinterpret_cast<const bf8_t*>(abase + (16 + llo) * 512 + (kb ^ swz));
#pragma unroll
      for (int nf = 0; nf < 4; ++nf) {
        acc[0][nf] = __builtin_amdgcn_mfma_f32_16x16x32_bf16(a0, bfr[nf][kk], acc[0][nf], 0, 0, 0);
        acc[1][nf] = __builtin_amdgcn_mfma_f32_16x16x32_bf16(a1, bfr[nf][kk], acc[1][nf], 0, 0, 0);
      }
    }

    // ---- pooling (gid sorted) ----
    int base = tile * 32;
    int gA = gid[base], gB = gid[base + 31];
    if (gA == gB) {
      if (gA != cur_g) {
#pragma unroll
        for (int nf = 0; nf < 4; ++nf) {
          if (pooled[nf] != 0.f)
            atomicAdd(&gsum[cur_g * kDhid + wave * 64 + nf * 16 + llo], pooled[nf]);
          pooled[nf] = 0.f;
        }
        cur_g = gA;
      }
#pragma unroll
      for (int nf = 0; nf < 4; ++nf) {
        float s = 0.f;
#pragma unroll
        for (int mf = 0; mf < 2; ++mf)
#pragma unroll
          for (int q = 0; q < 4; ++q) s += fmaxf(acc[mf][nf][q] + bv[nf], 0.f);
        pooled[nf] += s;
      }
    } else {
      // boundary tile (rare): per-element atomics, pooled untouched
#pragma unroll
      for (int mf = 0; mf < 2; ++mf)
#pragma unroll
        for (int q = 0; q < 4; ++q) {
          int r = base + mf * 16 + lhi * 4 + q;
          int g = gid[r];
#pragma unroll
          for (int nf = 0; nf < 4; ++nf) {
            float v = fmaxf(acc[mf][nf][q] + bv[nf], 0.f);
            if (v != 0.f) atomicAdd(&gsum[g * kDhid + wave * 64 + nf * 16 + llo], v);
          }
        }
    }
    __syncthreads();   // drains vmcnt: next buffer staged; this buffer free
  }

#pragma unroll
  for (int nf = 0; nf < 4; ++nf)
    if (pooled[nf] != 0.f)
      atomicAdd(&gsum[cur_g * kDhid + wave * 64 + nf * 16 + llo], pooled[nf]);
}

// ---------------------------------------------------------------------------
// head: out[g] = (gsum[g]/cnt[g]) @ Wp + bp, cnt via binary search on gid.
// ---------------------------------------------------------------------------
__global__ void head_kernel(const float* __restrict__ gsum,
                            const float* __restrict__ Wp,
                            const float* __restrict__ bp,
                            const int* __restrict__ gid,
                            float* __restrict__ out) {
  int g = blockIdx.x;
  int c = threadIdx.x;
  int lo0 = 0, hi0 = kNodes;
  while (lo0 < hi0) { int m = (lo0 + hi0) >> 1; if (gid[m] < g) lo0 = m + 1; else hi0 = m; }
  int lo1 = lo0, hi1 = kNodes;
  while (lo1 < hi1) { int m = (lo1 + hi1) >> 1; if (gid[m] < g + 1) lo1 = m + 1; else hi1 = m; }
  float rc = 1.0f / fmaxf((float)(lo1 - lo0), 1.0f);
  if (c < kClasses) {
    float acc = bp[c];
    for (int k = 0; k < kDhid; ++k)
      acc += gsum[g * kDhid + k] * rc * Wp[k * kClasses + c];
    out[g * kClasses + c] = acc;
  }
}

// ---------------------------------------------------------------------------
extern "C" void kernel_launch(void* const* d_in, const int* in_sizes, int n_in,
                              void* d_out, int out_size, void* d_ws, size_t ws_size,
                              hipStream_t stream) {
  const float* h  = (const float*)d_in[0];
  const float* Ws = (const float*)d_in[1];
  const float* Wn = (const float*)d_in[2];
  const float* b  = (const float*)d_in[3];
  const float* Wp = (const float*)d_in[4];
  const float* bp = (const float*)d_in[5];
  const int* src  = (const int*)d_in[6];
  const int* dst  = (const int*)d_in[7];
  const int* gid  = (const int*)d_in[8];
  float* out = (float*)d_out;

  char* ws = (char*)d_ws;
  // pairs (12.8MB) aliases A16 (51.2MB): pairs dead before cvt_h runs.
  const size_t a16Off      = 0;             // 100000*256*2 = 51,200,000
  const size_t wtOff       = 51249152;      // 131,072
  const size_t csrOff      = 51380224;      // 6,400,000
  const size_t rowOff      = 57780224;      // 400,016 (100001*4 padded)
  const size_t gsumOff     = 58180240;      // 65,536
  const size_t bktStartOff = 58245776;      // 800 ((196+1)*4 padded)
  const size_t bktCurOff   = 58246576;      // 800
  ushort* A16   = (ushort*)(ws + a16Off);
  int2* pairs   = (int2*)(ws + a16Off);
  ushort* Wt    = (ushort*)(ws + wtOff);
  int* csr      = (int*)(ws + csrOff);
  int* row      = (int*)(ws + rowOff);
  float* gsum   = (float*)(ws + gsumOff);
  int* bktStart = (int*)(ws + bktStartOff);
  int* bktCur   = (int*)(ws + bktCurOff);

  // zero gsum + bktStart + bktCursor (contiguous)
  hipMemsetAsync(ws + gsumOff, 0, (58246576 + 800) - 58180240, stream);

  hipLaunchKernelGGL(bucket_count, dim3(kEBlocks), dim3(256), 0, stream, dst, bktCur);
  hipLaunchKernelGGL(bucket_starts, dim3(1), dim3(256), 0, stream, bktCur, bktStart);
  hipLaunchKernelGGL(bucket_scatter, dim3(kEBlocks), dim3(256), 0, stream, src, dst, bktCur, pairs);
  hipLaunchKernelGGL(bucket_fill, dim3(NB), dim3(512), 0, stream, pairs, bktStart, row, csr);

  hipLaunchKernelGGL(cvt_h, dim3((kNodes * 32 + 255) / 256), dim3(256), 0, stream, h, A16);
  hipLaunchKernelGGL(cvt_w, dim3((kK * kDhid + 255) / 256), dim3(256), 0, stream, Ws, Wn, Wt);
  hipLaunchKernelGGL(aggregate, dim3((kNodes + 3) / 4), dim3(256), 0, stream, A16, row, csr);

  hipLaunchKernelGGL(gemm_pool, dim3(kGemmBlocks), dim3(256), 0, stream,
                     A16, Wt, b, gid, gsum);
  hipLaunchKernelGGL(head_kernel, dim3(kGraphs), dim3(64), 0, stream,
                     gsum, Wp, bp, gid, out);
}

// Round 7
// 191.066 us; speedup vs baseline: 47.0588x; 1.0748x over previous
//
#include <hip/hip_runtime.h>
#include <stdint.h>

constexpr int kNodes    = 100000;
constexpr int kEdges    = 1600000;
constexpr int kDin      = 128;
constexpr int kK        = 256;      // concat K = [h | h_neigh]
constexpr int kDhid     = 256;
constexpr int kClasses  = 40;
constexpr int kGraphs   = 64;

constexpr int kBktShift = 9;                       // 512 nodes per bucket
constexpr int NB = (kNodes + 511) >> 9;            // 196 buckets
constexpr int kChunk = 6250;                       // edges per block in count/scatter
constexpr int kEBlocks = (kEdges + kChunk - 1) / kChunk;  // 256

constexpr int kTPB = 5;                            // row-tiles (32 rows) per gemm block
constexpr int kTiles = kNodes / 32;                // 3125
constexpr int kGemmBlocks = kTiles / kTPB;         // 625

typedef __attribute__((ext_vector_type(8))) short bf8_t;   // 8 x bf16 (4 VGPR)
typedef __attribute__((ext_vector_type(4))) float f4_t;    // mfma C/D

__device__ inline ushort f2bf(float f) {
  uint32_t u = __float_as_uint(f);
  u += 0x7fff + ((u >> 16) & 1);          // RNE
  return (ushort)(u >> 16);
}

// ---------------------------------------------------------------------------
// Bucketed CSR build: count -> starts -> scatter pairs -> per-bucket fill
// ---------------------------------------------------------------------------
__global__ void bucket_count(const int* __restrict__ dst, int* __restrict__ bktCursor) {
  __shared__ int hist[NB];
  for (int i = threadIdx.x; i < NB; i += 256) hist[i] = 0;
  __syncthreads();
  int e0 = blockIdx.x * kChunk;
  int e1 = min(e0 + kChunk, kEdges);
  for (int e = e0 + threadIdx.x; e < e1; e += 256)
    atomicAdd(&hist[dst[e] >> kBktShift], 1);
  __syncthreads();
  for (int i = threadIdx.x; i < NB; i += 256)
    if (hist[i]) atomicAdd(&bktCursor[i], hist[i]);
}

__global__ void bucket_starts(int* __restrict__ bktCursor, int* __restrict__ bktStart) {
  __shared__ int s[256];
  int t = threadIdx.x;
  int v = (t < NB) ? bktCursor[t] : 0;
  s[t] = v;
  __syncthreads();
#pragma unroll
  for (int off = 1; off < 256; off <<= 1) {
    int u = (t >= off) ? s[t - off] : 0;
    __syncthreads();
    s[t] += u;
    __syncthreads();
  }
  int excl = s[t] - v;
  if (t < NB) { bktStart[t] = excl; bktCursor[t] = excl; }
  if (t == NB - 1) bktStart[NB] = s[t];
}

__global__ void bucket_scatter(const int* __restrict__ src, const int* __restrict__ dst,
                               int* __restrict__ bktCursor, int2* __restrict__ pairs) {
  __shared__ int hist[NB], base[NB], cur[NB];
  for (int i = threadIdx.x; i < NB; i += 256) { hist[i] = 0; cur[i] = 0; }
  __syncthreads();
  int e0 = blockIdx.x * kChunk;
  int e1 = min(e0 + kChunk, kEdges);
  for (int e = e0 + threadIdx.x; e < e1; e += 256)
    atomicAdd(&hist[dst[e] >> kBktShift], 1);
  __syncthreads();
  for (int i = threadIdx.x; i < NB; i += 256)
    base[i] = hist[i] ? atomicAdd(&bktCursor[i], hist[i]) : 0;
  __syncthreads();
  for (int e = e0 + threadIdx.x; e < e1; e += 256) {
    int d = dst[e];
    int b = d >> kBktShift;
    int p = atomicAdd(&cur[b], 1);
    pairs[base[b] + p] = make_int2(src[e], d);
  }
}

__global__ void bucket_fill(const int2* __restrict__ pairs, const int* __restrict__ bktStart,
                            int* __restrict__ row, int* __restrict__ csr) {
  __shared__ int deg[512], scn[512], cur[512];
  int b = blockIdx.x;
  int t = threadIdx.x;
  int e0 = bktStart[b], e1 = bktStart[b + 1];
  int nb0 = b << kBktShift;
  deg[t] = 0;
  __syncthreads();
  for (int e = e0 + t; e < e1; e += 512)
    atomicAdd(&deg[pairs[e].y - nb0], 1);
  __syncthreads();
  int d = deg[t];
  scn[t] = d;
  __syncthreads();
#pragma unroll
  for (int off = 1; off < 512; off <<= 1) {
    int u = (t >= off) ? scn[t - off] : 0;
    __syncthreads();
    scn[t] += u;
    __syncthreads();
  }
  int excl = scn[t] - d;
  cur[t] = excl;
  int n = nb0 + t;
  if (n <= kNodes) row[n] = e0 + excl;
  __syncthreads();
  for (int e = e0 + t; e < e1; e += 512) {
    int2 pr = pairs[e];
    int p = atomicAdd(&cur[pr.y - nb0], 1);
    csr[e0 + p] = pr.x;
  }
}

// ---------------------------------------------------------------------------
// cvt_hw: fused  h fp32 -> A16[n][0..127] bf16  AND  Wt build (transposed,
// stacked [Ws;Wn]).  Block-range split; exact grid.
// ---------------------------------------------------------------------------
__global__ void cvt_hw(const float* __restrict__ h, const float* __restrict__ Ws,
                       const float* __restrict__ Wn, ushort* __restrict__ A16,
                       ushort* __restrict__ Wt) {
  int t = blockIdx.x * 256 + threadIdx.x;
  const int hN = kNodes * 32;          // 3,200,000 float4-quads
  if (t < hN) {
    int n = t >> 5;
    int c4 = (t & 31) * 4;
    float4 v = *reinterpret_cast<const float4*>(h + (size_t)n * kDin + c4);
    ushort4 o;
    o.x = f2bf(v.x); o.y = f2bf(v.y); o.z = f2bf(v.z); o.w = f2bf(v.w);
    *reinterpret_cast<ushort4*>(A16 + (size_t)n * kK + c4) = o;
  } else {
    int u = t - hN;                    // 0 .. 65535
    int j = u & 255;
    int k = u >> 8;
    float v = (k < 128) ? Ws[(size_t)k * kDhid + j] : Wn[(size_t)(k - 128) * kDhid + j];
    Wt[(size_t)j * kK + k] = f2bf(v);
  }
}

// ---------------------------------------------------------------------------
// aggregate v2: 4 x 16-lane groups per wave, each group gathers a DIFFERENT
// neighbor row (16 lanes x 16B = 256B row).  unroll 2 => 8 rows in flight
// per wave.  Cross-group shfl_xor butterfly; group 0 writes packed row.
// ---------------------------------------------------------------------------
__global__ void aggregate(ushort* __restrict__ A16, const int* __restrict__ row,
                          const int* __restrict__ csr) {
  int n = blockIdx.x * 4 + (threadIdx.x >> 6);
  if (n >= kNodes) return;
  int lane = threadIdx.x & 63;
  int grp = lane >> 4;      // 0..3: neighbor slot
  int sub = lane & 15;      // 0..15: 16B column chunk
  int s0 = row[n], s1 = row[n + 1];
  float a0 = 0.f, a1 = 0.f, a2 = 0.f, a3 = 0.f, a4 = 0.f, a5 = 0.f, a6 = 0.f, a7 = 0.f;
#pragma unroll 2
  for (int i = s0 + grp; i < s1; i += 4) {
    int s = csr[i];
    uint4 v = *reinterpret_cast<const uint4*>((const char*)A16 + (size_t)s * 512 + sub * 16);
    a0 += __uint_as_float(v.x << 16);  a1 += __uint_as_float(v.x & 0xffff0000u);
    a2 += __uint_as_float(v.y << 16);  a3 += __uint_as_float(v.y & 0xffff0000u);
    a4 += __uint_as_float(v.z << 16);  a5 += __uint_as_float(v.z & 0xffff0000u);
    a6 += __uint_as_float(v.w << 16);  a7 += __uint_as_float(v.w & 0xffff0000u);
  }
  // butterfly across the 4 groups (lanes ^16, ^32)
#pragma unroll
  for (int m = 16; m <= 32; m <<= 1) {
    a0 += __shfl_xor(a0, m, 64); a1 += __shfl_xor(a1, m, 64);
    a2 += __shfl_xor(a2, m, 64); a3 += __shfl_xor(a3, m, 64);
    a4 += __shfl_xor(a4, m, 64); a5 += __shfl_xor(a5, m, 64);
    a6 += __shfl_xor(a6, m, 64); a7 += __shfl_xor(a7, m, 64);
  }
  if (grp == 0) {
    float rd = 1.f / fmaxf((float)(s1 - s0), 1.f);
    uint4 o;
    o.x = (uint32_t)f2bf(a0 * rd) | ((uint32_t)f2bf(a1 * rd) << 16);
    o.y = (uint32_t)f2bf(a2 * rd) | ((uint32_t)f2bf(a3 * rd) << 16);
    o.z = (uint32_t)f2bf(a4 * rd) | ((uint32_t)f2bf(a5 * rd) << 16);
    o.w = (uint32_t)f2bf(a6 * rd) | ((uint32_t)f2bf(a7 * rd) << 16);
    *reinterpret_cast<uint4*>((char*)A16 + (size_t)n * 512 + 256 + sub * 16) = o;
  }
}

// ---------------------------------------------------------------------------
// gemm_pool v2: W-stationary streaming.  4 waves, wave owns 64 cols; B frags
// in registers; 5 row-tiles of 32 rows via double-buffered 16KB LDS A-tiles
// (global_load_lds, prefetch-before-compute).  Register pooling (gid sorted).
// ---------------------------------------------------------------------------
__global__ __launch_bounds__(256, 2)
void gemm_pool(const ushort* __restrict__ A16, const ushort* __restrict__ Wt,
               const float* __restrict__ bias, const int* __restrict__ gid,
               float* __restrict__ gsum) {
  __shared__ ushort Abuf[2][32 * 256];   // 2 x 16 KB
  const int tid  = threadIdx.x;
  const int lane = tid & 63;
  const int wave = tid >> 6;             // col-slice: wave*64 .. +64
  const int lhi = lane >> 4;
  const int llo = lane & 15;

  bf8_t bfr[4][8];
#pragma unroll
  for (int nf = 0; nf < 4; ++nf) {
    const char* wrow = (const char*)Wt + (size_t)(wave * 64 + nf * 16 + llo) * 512 + lhi * 16;
#pragma unroll
    for (int kk = 0; kk < 8; ++kk)
      bfr[nf][kk] = *reinterpret_cast<const bf8_t*>(wrow + kk * 64);
  }
  float bv[4];
#pragma unroll
  for (int nf = 0; nf < 4; ++nf) bv[nf] = bias[wave * 64 + nf * 16 + llo];

  auto stage = [&](int buf, int tile) {
#pragma unroll
    for (int i = 0; i < 4; ++i) {
      int r = i * 8 + (tid >> 5);
      int wb = (tid & 31) * 16;
      size_t gsrc = ((size_t)tile * 32 + r) * 512 + (size_t)(wb ^ ((r & 7) << 4));
      uint32_t ldst = (uint32_t)(i * 4096 + tid * 16);
      __builtin_amdgcn_global_load_lds(
          (const __attribute__((address_space(1))) uint32_t*)((const char*)A16 + gsrc),
          (__attribute__((address_space(3))) uint32_t*)((char*)&Abuf[buf][0] + ldst),
          16, 0, 0);
    }
  };

  const int t0 = blockIdx.x * kTPB;
  stage(0, t0);
  __syncthreads();

  float pooled[4] = {0.f, 0.f, 0.f, 0.f};
  int cur_g = gid[t0 * 32];

  for (int ti = 0; ti < kTPB; ++ti) {
    int tile = t0 + ti;
    if (ti + 1 < kTPB) stage((ti + 1) & 1, tile + 1);

    f4_t acc[2][4];
#pragma unroll
    for (int mf = 0; mf < 2; ++mf)
#pragma unroll
      for (int nf = 0; nf < 4; ++nf) acc[mf][nf] = (f4_t)0.f;
    const char* abase = (const char*)&Abuf[ti & 1][0];
    const int swz = (llo & 7) << 4;
#pragma unroll
    for (int kk = 0; kk < 8; ++kk) {
      int kb = kk * 64 + lhi * 16;
      bf8_t x0 = *reinterpret_cast<const bf8_t*>(abase + llo * 512 + (kb ^ swz));
      bf8_t x1 = *reinterpret_cast<const bf8_t*>(abase + (16 + llo) * 512 + (kb ^ swz));
#pragma unroll
      for (int nf = 0; nf < 4; ++nf) {
        acc[0][nf] = __builtin_amdgcn_mfma_f32_16x16x32_bf16(x0, bfr[nf][kk], acc[0][nf], 0, 0, 0);
        acc[1][nf] = __builtin_amdgcn_mfma_f32_16x16x32_bf16(x1, bfr[nf][kk], acc[1][nf], 0, 0, 0);
      }
    }

    int base = tile * 32;
    int gA = gid[base], gB = gid[base + 31];
    if (gA == gB) {
      if (gA != cur_g) {
#pragma unroll
        for (int nf = 0; nf < 4; ++nf) {
          if (pooled[nf] != 0.f)
            atomicAdd(&gsum[cur_g * kDhid + wave * 64 + nf * 16 + llo], pooled[nf]);
          pooled[nf] = 0.f;
        }
        cur_g = gA;
      }
#pragma unroll
      for (int nf = 0; nf < 4; ++nf) {
        float s = 0.f;
#pragma unroll
        for (int mf = 0; mf < 2; ++mf)
#pragma unroll
          for (int q = 0; q < 4; ++q) s += fmaxf(acc[mf][nf][q] + bv[nf], 0.f);
        pooled[nf] += s;
      }
    } else {
#pragma unroll
      for (int mf = 0; mf < 2; ++mf)
#pragma unroll
        for (int q = 0; q < 4; ++q) {
          int r = base + mf * 16 + lhi * 4 + q;
          int g = gid[r];
#pragma unroll
          for (int nf = 0; nf < 4; ++nf) {
            float v = fmaxf(acc[mf][nf][q] + bv[nf], 0.f);
            if (v != 0.f) atomicAdd(&gsum[g * kDhid + wave * 64 + nf * 16 + llo], v);
          }
        }
    }
    __syncthreads();
  }

#pragma unroll
  for (int nf = 0; nf < 4; ++nf)
    if (pooled[nf] != 0.f)
      atomicAdd(&gsum[cur_g * kDhid + wave * 64 + nf * 16 + llo], pooled[nf]);
}

// ---------------------------------------------------------------------------
// head: out[g] = (gsum[g]/cnt[g]) @ Wp + bp, cnt via binary search on gid.
// ---------------------------------------------------------------------------
__global__ void head_kernel(const float* __restrict__ gsum,
                            const float* __restrict__ Wp,
                            const float* __restrict__ bp,
                            const int* __restrict__ gid,
                            float* __restrict__ out) {
  int g = blockIdx.x;
  int c = threadIdx.x;
  int lo0 = 0, hi0 = kNodes;
  while (lo0 < hi0) { int m = (lo0 + hi0) >> 1; if (gid[m] < g) lo0 = m + 1; else hi0 = m; }
  int lo1 = lo0, hi1 = kNodes;
  while (lo1 < hi1) { int m = (lo1 + hi1) >> 1; if (gid[m] < g + 1) lo1 = m + 1; else hi1 = m; }
  float rc = 1.0f / fmaxf((float)(lo1 - lo0), 1.0f);
  if (c < kClasses) {
    float acc = bp[c];
    for (int k = 0; k < kDhid; ++k)
      acc += gsum[g * kDhid + k] * rc * Wp[k * kClasses + c];
    out[g * kClasses + c] = acc;
  }
}

// ---------------------------------------------------------------------------
extern "C" void kernel_launch(void* const* d_in, const int* in_sizes, int n_in,
                              void* d_out, int out_size, void* d_ws, size_t ws_size,
                              hipStream_t stream) {
  const float* h  = (const float*)d_in[0];
  const float* Ws = (const float*)d_in[1];
  const float* Wn = (const float*)d_in[2];
  const float* b  = (const float*)d_in[3];
  const float* Wp = (const float*)d_in[4];
  const float* bp = (const float*)d_in[5];
  const int* src  = (const int*)d_in[6];
  const int* dst  = (const int*)d_in[7];
  const int* gid  = (const int*)d_in[8];
  float* out = (float*)d_out;

  char* ws = (char*)d_ws;
  // pairs (12.8MB) aliases A16 (51.2MB): pairs dead before cvt_hw runs.
  const size_t a16Off      = 0;             // 100000*256*2 = 51,200,000
  const size_t wtOff       = 51249152;      // 131,072
  const size_t csrOff      = 51380224;      // 6,400,000
  const size_t rowOff      = 57780224;      // 400,016 (100001*4 padded)
  const size_t gsumOff     = 58180240;      // 65,536
  const size_t bktStartOff = 58245776;      // 800 ((196+1)*4 padded)
  const size_t bktCurOff   = 58246576;      // 800
  ushort* A16   = (ushort*)(ws + a16Off);
  int2* pairs   = (int2*)(ws + a16Off);
  ushort* Wt    = (ushort*)(ws + wtOff);
  int* csr      = (int*)(ws + csrOff);
  int* row      = (int*)(ws + rowOff);
  float* gsum   = (float*)(ws + gsumOff);
  int* bktStart = (int*)(ws + bktStartOff);
  int* bktCur   = (int*)(ws + bktCurOff);

  hipMemsetAsync(ws + gsumOff, 0, (58246576 + 800) - 58180240, stream);

  hipLaunchKernelGGL(bucket_count, dim3(kEBlocks), dim3(256), 0, stream, dst, bktCur);
  hipLaunchKernelGGL(bucket_starts, dim3(1), dim3(256), 0, stream, bktCur, bktStart);
  hipLaunchKernelGGL(bucket_scatter, dim3(kEBlocks), dim3(256), 0, stream, src, dst, bktCur, pairs);
  hipLaunchKernelGGL(bucket_fill, dim3(NB), dim3(512), 0, stream, pairs, bktStart, row, csr);

  hipLaunchKernelGGL(cvt_hw, dim3((kNodes * 32 + kK * kDhid) / 256), dim3(256), 0, stream,
                     h, Ws, Wn, A16, Wt);
  hipLaunchKernelGGL(aggregate, dim3((kNodes + 3) / 4), dim3(256), 0, stream, A16, row, csr);

  hipLaunchKernelGGL(gemm_pool, dim3(kGemmBlocks), dim3(256), 0, stream,
                     A16, Wt, b, gid, gsum);
  hipLaunchKernelGGL(head_kernel, dim3(kGraphs), dim3(64), 0, stream,
                     gsum, Wp, bp, gid, out);
}

// Round 8
// 172.861 us; speedup vs baseline: 52.0148x; 1.1053x over previous
//
#include <hip/hip_runtime.h>
#include <stdint.h>

constexpr int kNodes    = 100000;
constexpr int kEdges    = 1600000;
constexpr int kDin      = 128;
constexpr int kK        = 256;      // concat K = [h | h_neigh]
constexpr int kDhid     = 256;
constexpr int kClasses  = 40;
constexpr int kGraphs   = 64;

constexpr int kBktShift = 8;                       // 256 nodes per bucket
constexpr int NB = (kNodes + 255) >> 8;            // 392 buckets
constexpr int kBktCap = 5120;                      // mean 4082, sigma 64 -> 16 sigma
constexpr int kChunk = 6250;                       // edges per block in scatter
constexpr int kEBlocks = (kEdges + kChunk - 1) / kChunk;  // 256

constexpr int kTPB = 5;                            // row-tiles (32 rows) per gemm block
constexpr int kTiles = kNodes / 32;                // 3125
constexpr int kGemmBlocks = kTiles / kTPB;         // 625

typedef __attribute__((ext_vector_type(8))) short bf8_t;   // 8 x bf16 (4 VGPR)
typedef __attribute__((ext_vector_type(4))) float f4_t;    // mfma C/D

__device__ inline ushort f2bf(float f) {
  uint32_t u = __float_as_uint(f);
  u += 0x7fff + ((u >> 16) & 1);          // RNE
  return (ushort)(u >> 16);
}

// ---------------------------------------------------------------------------
// bucket_scatter: fixed-capacity buckets, packed 4B pairs (src<<8 | dlocal).
// LDS histogram -> one global atomic per touched bucket -> scattered writes.
// ---------------------------------------------------------------------------
__global__ void bucket_scatter(const int* __restrict__ src, const int* __restrict__ dst,
                               int* __restrict__ bktCur, uint32_t* __restrict__ pairs) {
  __shared__ int hist[NB], base[NB], cur[NB];
  for (int i = threadIdx.x; i < NB; i += 256) { hist[i] = 0; cur[i] = 0; }
  __syncthreads();
  int e0 = blockIdx.x * kChunk;
  int e1 = min(e0 + kChunk, kEdges);
  for (int e = e0 + threadIdx.x; e < e1; e += 256)
    atomicAdd(&hist[dst[e] >> kBktShift], 1);
  __syncthreads();
  for (int i = threadIdx.x; i < NB; i += 256)
    base[i] = hist[i] ? atomicAdd(&bktCur[i], hist[i]) : 0;
  __syncthreads();
  for (int e = e0 + threadIdx.x; e < e1; e += 256) {
    int d = dst[e];
    int b = d >> kBktShift;
    int p = atomicAdd(&cur[b], 1);
    pairs[(size_t)b * kBktCap + base[b] + p] = ((uint32_t)src[e] << 8) | (uint32_t)(d & 255);
  }
}

// ---------------------------------------------------------------------------
// bucket_fill: one block per bucket.  LDS degree hist -> scan -> row/rend +
// csr (gapped layout, base = b*kBktCap).
// ---------------------------------------------------------------------------
__global__ void bucket_fill(const uint32_t* __restrict__ pairs, const int* __restrict__ bktCur,
                            int* __restrict__ row, int* __restrict__ rend,
                            int* __restrict__ csr) {
  __shared__ int deg[256], scn[256], cur[256];
  int b = blockIdx.x;
  int t = threadIdx.x;
  int cnt = bktCur[b];
  int e0 = b * kBktCap;
  int nb0 = b << kBktShift;
  deg[t] = 0;
  __syncthreads();
  for (int e = t; e < cnt; e += 256)
    atomicAdd(&deg[pairs[e0 + e] & 255u], 1);
  __syncthreads();
  int d = deg[t];
  scn[t] = d;
  __syncthreads();
#pragma unroll
  for (int off = 1; off < 256; off <<= 1) {
    int u = (t >= off) ? scn[t - off] : 0;
    __syncthreads();
    scn[t] += u;
    __syncthreads();
  }
  int excl = scn[t] - d;
  cur[t] = excl;
  int n = nb0 + t;
  if (n < kNodes) { row[n] = e0 + excl; rend[n] = e0 + scn[t]; }
  __syncthreads();
  for (int e = t; e < cnt; e += 256) {
    uint32_t pr = pairs[e0 + e];
    int p = atomicAdd(&cur[pr & 255u], 1);
    csr[e0 + p] = (int)(pr >> 8);
  }
}

// ---------------------------------------------------------------------------
// cvt_hw: fused  h fp32 -> A16[n][0..127] bf16  AND  Wt build (transposed,
// stacked [Ws;Wn]).  Block-range split; exact grid.
// ---------------------------------------------------------------------------
__global__ void cvt_hw(const float* __restrict__ h, const float* __restrict__ Ws,
                       const float* __restrict__ Wn, ushort* __restrict__ A16,
                       ushort* __restrict__ Wt) {
  int t = blockIdx.x * 256 + threadIdx.x;
  const int hN = kNodes * 32;          // 3,200,000 float4-quads
  if (t < hN) {
    int n = t >> 5;
    int c4 = (t & 31) * 4;
    float4 v = *reinterpret_cast<const float4*>(h + (size_t)n * kDin + c4);
    ushort4 o;
    o.x = f2bf(v.x); o.y = f2bf(v.y); o.z = f2bf(v.z); o.w = f2bf(v.w);
    *reinterpret_cast<ushort4*>(A16 + (size_t)n * kK + c4) = o;
  } else {
    int u = t - hN;                    // 0 .. 65535
    int j = u & 255;
    int k = u >> 8;
    float v = (k < 128) ? Ws[(size_t)k * kDhid + j] : Wn[(size_t)(k - 128) * kDhid + j];
    Wt[(size_t)j * kK + k] = f2bf(v);
  }
}

// ---------------------------------------------------------------------------
// aggregate: 4 x 16-lane groups per wave, each group gathers a DIFFERENT
// neighbor row (16 lanes x 16B).  unroll 4 => 16 rows in flight per wave.
// Cross-group shfl_xor butterfly; group 0 writes packed row.
// ---------------------------------------------------------------------------
__global__ void aggregate(ushort* __restrict__ A16, const int* __restrict__ row,
                          const int* __restrict__ rend, const int* __restrict__ csr) {
  int n = blockIdx.x * 4 + (threadIdx.x >> 6);
  if (n >= kNodes) return;
  int lane = threadIdx.x & 63;
  int grp = lane >> 4;      // 0..3: neighbor slot
  int sub = lane & 15;      // 0..15: 16B column chunk
  int s0 = row[n], s1 = rend[n];
  float a0 = 0.f, a1 = 0.f, a2 = 0.f, a3 = 0.f, a4 = 0.f, a5 = 0.f, a6 = 0.f, a7 = 0.f;
#pragma unroll 4
  for (int i = s0 + grp; i < s1; i += 4) {
    int s = csr[i];
    uint4 v = *reinterpret_cast<const uint4*>((const char*)A16 + (size_t)s * 512 + sub * 16);
    a0 += __uint_as_float(v.x << 16);  a1 += __uint_as_float(v.x & 0xffff0000u);
    a2 += __uint_as_float(v.y << 16);  a3 += __uint_as_float(v.y & 0xffff0000u);
    a4 += __uint_as_float(v.z << 16);  a5 += __uint_as_float(v.z & 0xffff0000u);
    a6 += __uint_as_float(v.w << 16);  a7 += __uint_as_float(v.w & 0xffff0000u);
  }
  // butterfly across the 4 groups (lanes ^16, ^32)
#pragma unroll
  for (int m = 16; m <= 32; m <<= 1) {
    a0 += __shfl_xor(a0, m, 64); a1 += __shfl_xor(a1, m, 64);
    a2 += __shfl_xor(a2, m, 64); a3 += __shfl_xor(a3, m, 64);
    a4 += __shfl_xor(a4, m, 64); a5 += __shfl_xor(a5, m, 64);
    a6 += __shfl_xor(a6, m, 64); a7 += __shfl_xor(a7, m, 64);
  }
  if (grp == 0) {
    float rd = 1.f / fmaxf((float)(s1 - s0), 1.f);
    uint4 o;
    o.x = (uint32_t)f2bf(a0 * rd) | ((uint32_t)f2bf(a1 * rd) << 16);
    o.y = (uint32_t)f2bf(a2 * rd) | ((uint32_t)f2bf(a3 * rd) << 16);
    o.z = (uint32_t)f2bf(a4 * rd) | ((uint32_t)f2bf(a5 * rd) << 16);
    o.w = (uint32_t)f2bf(a6 * rd) | ((uint32_t)f2bf(a7 * rd) << 16);
    *reinterpret_cast<uint4*>((char*)A16 + (size_t)n * 512 + 256 + sub * 16) = o;
  }
}

// ---------------------------------------------------------------------------
// gemm_pool: W-stationary streaming.  4 waves, wave owns 64 cols; B frags
// in registers; 5 row-tiles of 32 rows via double-buffered 16KB LDS A-tiles
// (global_load_lds, prefetch-before-compute).  Register pooling (gid sorted).
// ---------------------------------------------------------------------------
__global__ __launch_bounds__(256, 2)
void gemm_pool(const ushort* __restrict__ A16, const ushort* __restrict__ Wt,
               const float* __restrict__ bias, const int* __restrict__ gid,
               float* __restrict__ gsum) {
  __shared__ ushort Abuf[2][32 * 256];   // 2 x 16 KB
  const int tid  = threadIdx.x;
  const int lane = tid & 63;
  const int wave = tid >> 6;             // col-slice: wave*64 .. +64
  const int lhi = lane >> 4;
  const int llo = lane & 15;

  bf8_t bfr[4][8];
#pragma unroll
  for (int nf = 0; nf < 4; ++nf) {
    const char* wrow = (const char*)Wt + (size_t)(wave * 64 + nf * 16 + llo) * 512 + lhi * 16;
#pragma unroll
    for (int kk = 0; kk < 8; ++kk)
      bfr[nf][kk] = *reinterpret_cast<const bf8_t*>(wrow + kk * 64);
  }
  float bv[4];
#pragma unroll
  for (int nf = 0; nf < 4; ++nf) bv[nf] = bias[wave * 64 + nf * 16 + llo];

  auto stage = [&](int buf, int tile) {
#pragma unroll
    for (int i = 0; i < 4; ++i) {
      int r = i * 8 + (tid >> 5);
      int wb = (tid & 31) * 16;
      size_t gsrc = ((size_t)tile * 32 + r) * 512 + (size_t)(wb ^ ((r & 7) << 4));
      uint32_t ldst = (uint32_t)(i * 4096 + tid * 16);
      __builtin_amdgcn_global_load_lds(
          (const __attribute__((address_space(1))) uint32_t*)((const char*)A16 + gsrc),
          (__attribute__((address_space(3))) uint32_t*)((char*)&Abuf[buf][0] + ldst),
          16, 0, 0);
    }
  };

  const int t0 = blockIdx.x * kTPB;
  stage(0, t0);
  __syncthreads();

  float pooled[4] = {0.f, 0.f, 0.f, 0.f};
  int cur_g = gid[t0 * 32];

  for (int ti = 0; ti < kTPB; ++ti) {
    int tile = t0 + ti;
    if (ti + 1 < kTPB) stage((ti + 1) & 1, tile + 1);

    f4_t acc[2][4];
#pragma unroll
    for (int mf = 0; mf < 2; ++mf)
#pragma unroll
      for (int nf = 0; nf < 4; ++nf) acc[mf][nf] = (f4_t)0.f;
    const char* abase = (const char*)&Abuf[ti & 1][0];
    const int swz = (llo & 7) << 4;
#pragma unroll
    for (int kk = 0; kk < 8; ++kk) {
      int kb = kk * 64 + lhi * 16;
      bf8_t x0 = *reinterpret_cast<const bf8_t*>(abase + llo * 512 + (kb ^ swz));
      bf8_t x1 = *reinterpret_cast<const bf8_t*>(abase + (16 + llo) * 512 + (kb ^ swz));
#pragma unroll
      for (int nf = 0; nf < 4; ++nf) {
        acc[0][nf] = __builtin_amdgcn_mfma_f32_16x16x32_bf16(x0, bfr[nf][kk], acc[0][nf], 0, 0, 0);
        acc[1][nf] = __builtin_amdgcn_mfma_f32_16x16x32_bf16(x1, bfr[nf][kk], acc[1][nf], 0, 0, 0);
      }
    }

    int base = tile * 32;
    int gA = gid[base], gB = gid[base + 31];
    if (gA == gB) {
      if (gA != cur_g) {
#pragma unroll
        for (int nf = 0; nf < 4; ++nf) {
          if (pooled[nf] != 0.f)
            atomicAdd(&gsum[cur_g * kDhid + wave * 64 + nf * 16 + llo], pooled[nf]);
          pooled[nf] = 0.f;
        }
        cur_g = gA;
      }
#pragma unroll
      for (int nf = 0; nf < 4; ++nf) {
        float s = 0.f;
#pragma unroll
        for (int mf = 0; mf < 2; ++mf)
#pragma unroll
          for (int q = 0; q < 4; ++q) s += fmaxf(acc[mf][nf][q] + bv[nf], 0.f);
        pooled[nf] += s;
      }
    } else {
#pragma unroll
      for (int mf = 0; mf < 2; ++mf)
#pragma unroll
        for (int q = 0; q < 4; ++q) {
          int r = base + mf * 16 + lhi * 4 + q;
          int g = gid[r];
#pragma unroll
          for (int nf = 0; nf < 4; ++nf) {
            float v = fmaxf(acc[mf][nf][q] + bv[nf], 0.f);
            if (v != 0.f) atomicAdd(&gsum[g * kDhid + wave * 64 + nf * 16 + llo], v);
          }
        }
    }
    __syncthreads();
  }

#pragma unroll
  for (int nf = 0; nf < 4; ++nf)
    if (pooled[nf] != 0.f)
      atomicAdd(&gsum[cur_g * kDhid + wave * 64 + nf * 16 + llo], pooled[nf]);
}

// ---------------------------------------------------------------------------
// head: out[g] = (gsum[g]/cnt[g]) @ Wp + bp, cnt via binary search on gid.
// ---------------------------------------------------------------------------
__global__ void head_kernel(const float* __restrict__ gsum,
                            const float* __restrict__ Wp,
                            const float* __restrict__ bp,
                            const int* __restrict__ gid,
                            float* __restrict__ out) {
  int g = blockIdx.x;
  int c = threadIdx.x;
  int lo0 = 0, hi0 = kNodes;
  while (lo0 < hi0) { int m = (lo0 + hi0) >> 1; if (gid[m] < g) lo0 = m + 1; else hi0 = m; }
  int lo1 = lo0, hi1 = kNodes;
  while (lo1 < hi1) { int m = (lo1 + hi1) >> 1; if (gid[m] < g + 1) lo1 = m + 1; else hi1 = m; }
  float rc = 1.0f / fmaxf((float)(lo1 - lo0), 1.0f);
  if (c < kClasses) {
    float acc = bp[c];
    for (int k = 0; k < kDhid; ++k)
      acc += gsum[g * kDhid + k] * rc * Wp[k * kClasses + c];
    out[g * kClasses + c] = acc;
  }
}

// ---------------------------------------------------------------------------
extern "C" void kernel_launch(void* const* d_in, const int* in_sizes, int n_in,
                              void* d_out, int out_size, void* d_ws, size_t ws_size,
                              hipStream_t stream) {
  const float* h  = (const float*)d_in[0];
  const float* Ws = (const float*)d_in[1];
  const float* Wn = (const float*)d_in[2];
  const float* b  = (const float*)d_in[3];
  const float* Wp = (const float*)d_in[4];
  const float* bp = (const float*)d_in[5];
  const int* src  = (const int*)d_in[6];
  const int* dst  = (const int*)d_in[7];
  const int* gid  = (const int*)d_in[8];
  float* out = (float*)d_out;

  char* ws = (char*)d_ws;
  // pairs (8MB, packed u32) aliases A16 (51.2MB): pairs dead before cvt_hw.
  const size_t a16Off    = 0;             // 100000*256*2 = 51,200,000
  const size_t wtOff     = 51249152;      // 131,072
  const size_t csrOff    = 51380224;      // 392*5120*4 = 8,028,160
  const size_t rowOff    = 59408384;      // 400,000
  const size_t rendOff   = 59808384;      // 400,000
  const size_t gsumOff   = 60208384;      // 65,536
  const size_t bktCurOff = 60273920;      // 1,568
  ushort* A16     = (ushort*)(ws + a16Off);
  uint32_t* pairs = (uint32_t*)(ws + a16Off);
  ushort* Wt      = (ushort*)(ws + wtOff);
  int* csr        = (int*)(ws + csrOff);
  int* row        = (int*)(ws + rowOff);
  int* rend       = (int*)(ws + rendOff);
  float* gsum     = (float*)(ws + gsumOff);
  int* bktCur     = (int*)(ws + bktCurOff);

  // zero gsum + bucket cursors (contiguous)
  hipMemsetAsync(ws + gsumOff, 0, (60273920 + 1568) - 60208384, stream);

  hipLaunchKernelGGL(bucket_scatter, dim3(kEBlocks), dim3(256), 0, stream, src, dst, bktCur, pairs);
  hipLaunchKernelGGL(bucket_fill, dim3(NB), dim3(256), 0, stream, pairs, bktCur, row, rend, csr);

  hipLaunchKernelGGL(cvt_hw, dim3((kNodes * 32 + kK * kDhid) / 256), dim3(256), 0, stream,
                     h, Ws, Wn, A16, Wt);
  hipLaunchKernelGGL(aggregate, dim3((kNodes + 3) / 4), dim3(256), 0, stream, A16, row, rend, csr);

  hipLaunchKernelGGL(gemm_pool, dim3(kGemmBlocks), dim3(256), 0, stream,
                     A16, Wt, b, gid, gsum);
  hipLaunchKernelGGL(head_kernel, dim3(kGraphs), dim3(64), 0, stream,
                     gsum, Wp, bp, gid, out);
}

// Round 10
// 165.959 us; speedup vs baseline: 54.1782x; 1.0416x over previous
//
#include <hip/hip_runtime.h>
#include <stdint.h>

constexpr int kNodes    = 100000;
constexpr int kEdges    = 1600000;
constexpr int kDin      = 128;
constexpr int kK        = 256;      // concat K = [h | h_neigh]
constexpr int kDhid     = 256;
constexpr int kClasses  = 40;
constexpr int kGraphs   = 64;

constexpr int kBktShift = 8;                       // 256 nodes per bucket
constexpr int NB = (kNodes + 255) >> 8;            // 392 buckets
constexpr int kBktCap = 5120;                      // mean 4082, sigma 64 -> 16 sigma
constexpr int kChunk = 6250;                       // edges per block in scatter
constexpr int kEBlocks = (kEdges + kChunk - 1) / kChunk;  // 256

constexpr int kTPB = 5;                            // row-tiles (32 rows) per gemm block
constexpr int kTiles = kNodes / 32;                // 3125
constexpr int kGemmBlocks = kTiles / kTPB;         // 625

typedef __attribute__((ext_vector_type(8))) short bf8_t;   // 8 x bf16 (4 VGPR)
typedef __attribute__((ext_vector_type(4))) float f4_t;    // mfma C/D
typedef __attribute__((ext_vector_type(2))) float f2_t;

__device__ inline ushort f2bf(float f) {
  uint32_t u = __float_as_uint(f);
  u += 0x7fff + ((u >> 16) & 1);          // RNE
  return (ushort)(u >> 16);
}

// ---- fp8 e4m3 helpers (HW cvt when available; manual fallback) ------------
template <bool HI>
__device__ inline f2_t fp8x2_f32(uint32_t w) {
#if __has_builtin(__builtin_amdgcn_cvt_pk_f32_fp8)
  return __builtin_amdgcn_cvt_pk_f32_fp8(w, HI);
#else
  f2_t r;
  uint32_t b0 = HI ? ((w >> 16) & 0xffu) : (w & 0xffu);
  uint32_t b1 = HI ? (w >> 24) : ((w >> 8) & 0xffu);
  auto dec = [](uint32_t b) -> float {
    uint32_t s = (b & 0x80u) << 24;
    uint32_t em = b & 0x7fu;
    float mag;
    if (em >= 0x08u) {
      uint32_t e = (em >> 3) - 7 + 127;
      mag = __uint_as_float((e << 23) | ((em & 7u) << 20));
    } else {
      mag = (float)em * 0.001953125f;   // em * 2^-9
    }
    return __uint_as_float(s | __float_as_uint(mag));
  };
  r.x = dec(b0); r.y = dec(b1);
  return r;
#endif
}

__device__ inline uint32_t f32_to_e4m3(float f) {
  uint32_t sgn = (__float_as_uint(f) >> 31) << 7;
  float mag = fabsf(f);
  uint32_t r;
  if (mag >= 0.015625f) {               // normal (>= 2^-6)
    uint32_t u = __float_as_uint(mag);
    u += 0x7FFFF + ((u >> 20) & 1);     // RNE to 3 mantissa bits
    int e = (int)(u >> 23) - 127;
    if (e > 8) r = 0x7Eu;               // clamp to 448
    else r = (uint32_t)((e + 7) << 3) | ((u >> 20) & 7u);
  } else {
    float m = mag * 512.f;              // 2^9
    int mi = (int)rintf(m);
    r = (mi > 7) ? 0x08u : (uint32_t)mi;
  }
  return r | sgn;
}

__device__ inline uint32_t pack4_e4m3(float x, float y, float z, float w) {
#if __has_builtin(__builtin_amdgcn_cvt_pk_fp8_f32)
  uint32_t p = __builtin_amdgcn_cvt_pk_fp8_f32(x, y, 0u, false);
  return __builtin_amdgcn_cvt_pk_fp8_f32(z, w, p, true);
#else
  return f32_to_e4m3(x) | (f32_to_e4m3(y) << 8) |
         (f32_to_e4m3(z) << 16) | (f32_to_e4m3(w) << 24);
#endif
}

// ---------------------------------------------------------------------------
// bucket_scatter: fixed-capacity buckets, packed 4B pairs (src<<8 | dlocal).
// ---------------------------------------------------------------------------
__global__ void bucket_scatter(const int* __restrict__ src, const int* __restrict__ dst,
                               int* __restrict__ bktCur, uint32_t* __restrict__ pairs) {
  __shared__ int hist[NB], base[NB], cur[NB];
  for (int i = threadIdx.x; i < NB; i += 256) { hist[i] = 0; cur[i] = 0; }
  __syncthreads();
  int e0 = blockIdx.x * kChunk;
  int e1 = min(e0 + kChunk, kEdges);
  for (int e = e0 + threadIdx.x; e < e1; e += 256)
    atomicAdd(&hist[dst[e] >> kBktShift], 1);
  __syncthreads();
  for (int i = threadIdx.x; i < NB; i += 256)
    base[i] = hist[i] ? atomicAdd(&bktCur[i], hist[i]) : 0;
  __syncthreads();
  for (int e = e0 + threadIdx.x; e < e1; e += 256) {
    int d = dst[e];
    int b = d >> kBktShift;
    int p = atomicAdd(&cur[b], 1);
    pairs[(size_t)b * kBktCap + base[b] + p] = ((uint32_t)src[e] << 8) | (uint32_t)(d & 255);
  }
}

// ---------------------------------------------------------------------------
// bucket_fill: one block per bucket.  LDS degree hist -> scan -> row/rend +
// csr (gapped layout, base = b*kBktCap).
// ---------------------------------------------------------------------------
__global__ void bucket_fill(const uint32_t* __restrict__ pairs, const int* __restrict__ bktCur,
                            int* __restrict__ row, int* __restrict__ rend,
                            int* __restrict__ csr) {
  __shared__ int deg[256], scn[256], cur[256];
  int b = blockIdx.x;
  int t = threadIdx.x;
  int cnt = bktCur[b];
  int e0 = b * kBktCap;
  int nb0 = b << kBktShift;
  deg[t] = 0;
  __syncthreads();
  for (int e = t; e < cnt; e += 256)
    atomicAdd(&deg[pairs[e0 + e] & 255u], 1);
  __syncthreads();
  int d = deg[t];
  scn[t] = d;
  __syncthreads();
#pragma unroll
  for (int off = 1; off < 256; off <<= 1) {
    int u = (t >= off) ? scn[t - off] : 0;
    __syncthreads();
    scn[t] += u;
    __syncthreads();
  }
  int excl = scn[t] - d;
  cur[t] = excl;
  int n = nb0 + t;
  if (n < kNodes) { row[n] = e0 + excl; rend[n] = e0 + scn[t]; }
  __syncthreads();
  for (int e = t; e < cnt; e += 256) {
    uint32_t pr = pairs[e0 + e];
    int p = atomicAdd(&cur[pr & 255u], 1);
    csr[e0 + p] = (int)(pr >> 8);
  }
}

// ---------------------------------------------------------------------------
// cvt_hw: h fp32 -> A16[n][0..127] bf16 (+H8 fp8 copy if enabled) AND Wt.
// ---------------------------------------------------------------------------
__global__ void cvt_hw(const float* __restrict__ h, const float* __restrict__ Ws,
                       const float* __restrict__ Wn, ushort* __restrict__ A16,
                       ushort* __restrict__ Wt, uint8_t* __restrict__ H8) {
  int t = blockIdx.x * 256 + threadIdx.x;
  const int hN = kNodes * 32;          // 3,200,000 float4-quads
  if (t < hN) {
    int n = t >> 5;
    int c4 = (t & 31) * 4;
    float4 v = *reinterpret_cast<const float4*>(h + (size_t)n * kDin + c4);
    ushort4 o;
    o.x = f2bf(v.x); o.y = f2bf(v.y); o.z = f2bf(v.z); o.w = f2bf(v.w);
    *reinterpret_cast<ushort4*>(A16 + (size_t)n * kK + c4) = o;
    if (H8)
      *reinterpret_cast<uint32_t*>(H8 + (size_t)n * kDin + c4) =
          pack4_e4m3(v.x, v.y, v.z, v.w);
  } else {
    int u = t - hN;                    // 0 .. 65535
    int j = u & 255;
    int k = u >> 8;
    float v = (k < 128) ? Ws[(size_t)k * kDhid + j] : Wn[(size_t)(k - 128) * kDhid + j];
    Wt[(size_t)j * kK + k] = f2bf(v);
  }
}

// ---------------------------------------------------------------------------
// aggregate8: gathers fp8 rows (128B = 2 lines).  4 x 16-lane groups per
// wave, each group one neighbor row; lane = 8B (8 fp8 -> 8 f32 via cvt_pk).
// unroll 4 => 16 rows in flight.  Butterfly; group 0 writes bf16 row.
// ---------------------------------------------------------------------------
__global__ void aggregate8(const uint8_t* __restrict__ H8, ushort* __restrict__ A16,
                           const int* __restrict__ row, const int* __restrict__ rend,
                           const int* __restrict__ csr) {
  int n = blockIdx.x * 4 + (threadIdx.x >> 6);
  if (n >= kNodes) return;
  int lane = threadIdx.x & 63;
  int grp = lane >> 4;      // 0..3: neighbor slot
  int sub = lane & 15;      // 0..15: 8B column chunk (cols sub*8..sub*8+7)
  int s0 = row[n], s1 = rend[n];
  float a0 = 0.f, a1 = 0.f, a2 = 0.f, a3 = 0.f, a4 = 0.f, a5 = 0.f, a6 = 0.f, a7 = 0.f;
#pragma unroll 4
  for (int i = s0 + grp; i < s1; i += 4) {
    int s = csr[i];
    uint2 v = *reinterpret_cast<const uint2*>(H8 + (size_t)s * kDin + sub * 8);
    f2_t l0 = fp8x2_f32<false>(v.x), h0 = fp8x2_f32<true>(v.x);
    f2_t l1 = fp8x2_f32<false>(v.y), h1 = fp8x2_f32<true>(v.y);
    a0 += l0.x; a1 += l0.y; a2 += h0.x; a3 += h0.y;
    a4 += l1.x; a5 += l1.y; a6 += h1.x; a7 += h1.y;
  }
#pragma unroll
  for (int m = 16; m <= 32; m <<= 1) {
    a0 += __shfl_xor(a0, m, 64); a1 += __shfl_xor(a1, m, 64);
    a2 += __shfl_xor(a2, m, 64); a3 += __shfl_xor(a3, m, 64);
    a4 += __shfl_xor(a4, m, 64); a5 += __shfl_xor(a5, m, 64);
    a6 += __shfl_xor(a6, m, 64); a7 += __shfl_xor(a7, m, 64);
  }
  if (grp == 0) {
    float rd = 1.f / fmaxf((float)(s1 - s0), 1.f);
    uint4 o;
    o.x = (uint32_t)f2bf(a0 * rd) | ((uint32_t)f2bf(a1 * rd) << 16);
    o.y = (uint32_t)f2bf(a2 * rd) | ((uint32_t)f2bf(a3 * rd) << 16);
    o.z = (uint32_t)f2bf(a4 * rd) | ((uint32_t)f2bf(a5 * rd) << 16);
    o.w = (uint32_t)f2bf(a6 * rd) | ((uint32_t)f2bf(a7 * rd) << 16);
    *reinterpret_cast<uint4*>((char*)A16 + (size_t)n * 512 + 256 + sub * 16) = o;
  }
}

// ---------------------------------------------------------------------------
// aggregate (bf16 fallback, used when ws too small for H8)
// ---------------------------------------------------------------------------
__global__ void aggregate(ushort* __restrict__ A16, const int* __restrict__ row,
                          const int* __restrict__ rend, const int* __restrict__ csr) {
  int n = blockIdx.x * 4 + (threadIdx.x >> 6);
  if (n >= kNodes) return;
  int lane = threadIdx.x & 63;
  int grp = lane >> 4;
  int sub = lane & 15;
  int s0 = row[n], s1 = rend[n];
  float a0 = 0.f, a1 = 0.f, a2 = 0.f, a3 = 0.f, a4 = 0.f, a5 = 0.f, a6 = 0.f, a7 = 0.f;
#pragma unroll 4
  for (int i = s0 + grp; i < s1; i += 4) {
    int s = csr[i];
    uint4 v = *reinterpret_cast<const uint4*>((const char*)A16 + (size_t)s * 512 + sub * 16);
    a0 += __uint_as_float(v.x << 16);  a1 += __uint_as_float(v.x & 0xffff0000u);
    a2 += __uint_as_float(v.y << 16);  a3 += __uint_as_float(v.y & 0xffff0000u);
    a4 += __uint_as_float(v.z << 16);  a5 += __uint_as_float(v.z & 0xffff0000u);
    a6 += __uint_as_float(v.w << 16);  a7 += __uint_as_float(v.w & 0xffff0000u);
  }
#pragma unroll
  for (int m = 16; m <= 32; m <<= 1) {
    a0 += __shfl_xor(a0, m, 64); a1 += __shfl_xor(a1, m, 64);
    a2 += __shfl_xor(a2, m, 64); a3 += __shfl_xor(a3, m, 64);
    a4 += __shfl_xor(a4, m, 64); a5 += __shfl_xor(a5, m, 64);
    a6 += __shfl_xor(a6, m, 64); a7 += __shfl_xor(a7, m, 64);
  }
  if (grp == 0) {
    float rd = 1.f / fmaxf((float)(s1 - s0), 1.f);
    uint4 o;
    o.x = (uint32_t)f2bf(a0 * rd) | ((uint32_t)f2bf(a1 * rd) << 16);
    o.y = (uint32_t)f2bf(a2 * rd) | ((uint32_t)f2bf(a3 * rd) << 16);
    o.z = (uint32_t)f2bf(a4 * rd) | ((uint32_t)f2bf(a5 * rd) << 16);
    o.w = (uint32_t)f2bf(a6 * rd) | ((uint32_t)f2bf(a7 * rd) << 16);
    *reinterpret_cast<uint4*>((char*)A16 + (size_t)n * 512 + 256 + sub * 16) = o;
  }
}

// ---------------------------------------------------------------------------
// gemm_pool: W-stationary streaming (unchanged).
// ---------------------------------------------------------------------------
__global__ __launch_bounds__(256, 2)
void gemm_pool(const ushort* __restrict__ A16, const ushort* __restrict__ Wt,
               const float* __restrict__ bias, const int* __restrict__ gid,
               float* __restrict__ gsum) {
  __shared__ ushort Abuf[2][32 * 256];   // 2 x 16 KB
  const int tid  = threadIdx.x;
  const int lane = tid & 63;
  const int wave = tid >> 6;
  const int lhi = lane >> 4;
  const int llo = lane & 15;

  bf8_t bfr[4][8];
#pragma unroll
  for (int nf = 0; nf < 4; ++nf) {
    const char* wrow = (const char*)Wt + (size_t)(wave * 64 + nf * 16 + llo) * 512 + lhi * 16;
#pragma unroll
    for (int kk = 0; kk < 8; ++kk)
      bfr[nf][kk] = *reinterpret_cast<const bf8_t*>(wrow + kk * 64);
  }
  float bv[4];
#pragma unroll
  for (int nf = 0; nf < 4; ++nf) bv[nf] = bias[wave * 64 + nf * 16 + llo];

  auto stage = [&](int buf, int tile) {
#pragma unroll
    for (int i = 0; i < 4; ++i) {
      int r = i * 8 + (tid >> 5);
      int wb = (tid & 31) * 16;
      size_t gsrc = ((size_t)tile * 32 + r) * 512 + (size_t)(wb ^ ((r & 7) << 4));
      uint32_t ldst = (uint32_t)(i * 4096 + tid * 16);
      __builtin_amdgcn_global_load_lds(
          (const __attribute__((address_space(1))) uint32_t*)((const char*)A16 + gsrc),
          (__attribute__((address_space(3))) uint32_t*)((char*)&Abuf[buf][0] + ldst),
          16, 0, 0);
    }
  };

  const int t0 = blockIdx.x * kTPB;
  stage(0, t0);
  __syncthreads();

  float pooled[4] = {0.f, 0.f, 0.f, 0.f};
  int cur_g = gid[t0 * 32];

  for (int ti = 0; ti < kTPB; ++ti) {
    int tile = t0 + ti;
    if (ti + 1 < kTPB) stage((ti + 1) & 1, tile + 1);

    f4_t acc[2][4];
#pragma unroll
    for (int mf = 0; mf < 2; ++mf)
#pragma unroll
      for (int nf = 0; nf < 4; ++nf) acc[mf][nf] = (f4_t)0.f;
    const char* abase = (const char*)&Abuf[ti & 1][0];
    const int swz = (llo & 7) << 4;
#pragma unroll
    for (int kk = 0; kk < 8; ++kk) {
      int kb = kk * 64 + lhi * 16;
      bf8_t x0 = *reinterpret_cast<const bf8_t*>(abase + llo * 512 + (kb ^ swz));
      bf8_t x1 = *reinterpret_cast<const bf8_t*>(abase + (16 + llo) * 512 + (kb ^ swz));
#pragma unroll
      for (int nf = 0; nf < 4; ++nf) {
        acc[0][nf] = __builtin_amdgcn_mfma_f32_16x16x32_bf16(x0, bfr[nf][kk], acc[0][nf], 0, 0, 0);
        acc[1][nf] = __builtin_amdgcn_mfma_f32_16x16x32_bf16(x1, bfr[nf][kk], acc[1][nf], 0, 0, 0);
      }
    }

    int base = tile * 32;
    int gA = gid[base], gB = gid[base + 31];
    if (gA == gB) {
      if (gA != cur_g) {
#pragma unroll
        for (int nf = 0; nf < 4; ++nf) {
          if (pooled[nf] != 0.f)
            atomicAdd(&gsum[cur_g * kDhid + wave * 64 + nf * 16 + llo], pooled[nf]);
          pooled[nf] = 0.f;
        }
        cur_g = gA;
      }
#pragma unroll
      for (int nf = 0; nf < 4; ++nf) {
        float s = 0.f;
#pragma unroll
        for (int mf = 0; mf < 2; ++mf)
#pragma unroll
          for (int q = 0; q < 4; ++q) s += fmaxf(acc[mf][nf][q] + bv[nf], 0.f);
        pooled[nf] += s;
      }
    } else {
#pragma unroll
      for (int mf = 0; mf < 2; ++mf)
#pragma unroll
        for (int q = 0; q < 4; ++q) {
          int r = base + mf * 16 + lhi * 4 + q;
          int g = gid[r];
#pragma unroll
          for (int nf = 0; nf < 4; ++nf) {
            float v = fmaxf(acc[mf][nf][q] + bv[nf], 0.f);
            if (v != 0.f) atomicAdd(&gsum[g * kDhid + wave * 64 + nf * 16 + llo], v);
          }
        }
    }
    __syncthreads();
  }

#pragma unroll
  for (int nf = 0; nf < 4; ++nf)
    if (pooled[nf] != 0.f)
      atomicAdd(&gsum[cur_g * kDhid + wave * 64 + nf * 16 + llo], pooled[nf]);
}

// ---------------------------------------------------------------------------
// head: out[g] = (gsum[g]/cnt[g]) @ Wp + bp, cnt via binary search on gid.
// ---------------------------------------------------------------------------
__global__ void head_kernel(const float* __restrict__ gsum,
                            const float* __restrict__ Wp,
                            const float* __restrict__ bp,
                            const int* __restrict__ gid,
                            float* __restrict__ out) {
  int g = blockIdx.x;
  int c = threadIdx.x;
  int lo0 = 0, hi0 = kNodes;
  while (lo0 < hi0) { int m = (lo0 + hi0) >> 1; if (gid[m] < g) lo0 = m + 1; else hi0 = m; }
  int lo1 = lo0, hi1 = kNodes;
  while (lo1 < hi1) { int m = (lo1 + hi1) >> 1; if (gid[m] < g + 1) lo1 = m + 1; else hi1 = m; }
  float rc = 1.0f / fmaxf((float)(lo1 - lo0), 1.0f);
  if (c < kClasses) {
    float acc = bp[c];
    for (int k = 0; k < kDhid; ++k)
      acc += gsum[g * kDhid + k] * rc * Wp[k * kClasses + c];
    out[g * kClasses + c] = acc;
  }
}

// ---------------------------------------------------------------------------
extern "C" void kernel_launch(void* const* d_in, const int* in_sizes, int n_in,
                              void* d_out, int out_size, void* d_ws, size_t ws_size,
                              hipStream_t stream) {
  const float* h  = (const float*)d_in[0];
  const float* Ws = (const float*)d_in[1];
  const float* Wn = (const float*)d_in[2];
  const float* b  = (const float*)d_in[3];
  const float* Wp = (const float*)d_in[4];
  const float* bp = (const float*)d_in[5];
  const int* src  = (const int*)d_in[6];
  const int* dst  = (const int*)d_in[7];
  const int* gid  = (const int*)d_in[8];
  float* out = (float*)d_out;

  char* ws = (char*)d_ws;
  // pairs (8MB, packed u32) aliases A16 (51.2MB): pairs dead before cvt_hw.
  const size_t a16Off    = 0;             // 100000*256*2 = 51,200,000
  const size_t wtOff     = 51249152;      // 131,072
  const size_t csrOff    = 51380224;      // 392*5120*4 = 8,028,160
  const size_t rowOff    = 59408384;      // 400,000
  const size_t rendOff   = 59808384;      // 400,000
  const size_t gsumOff   = 60208384;      // 65,536
  const size_t bktCurOff = 60273920;      // 1,568
  const size_t h8Off     = 60275712;      // 12,800,000 (fp8 gather table)
  const size_t needFp8   = h8Off + 12800000;  // 73,075,712
  ushort* A16     = (ushort*)(ws + a16Off);
  uint32_t* pairs = (uint32_t*)(ws + a16Off);
  ushort* Wt      = (ushort*)(ws + wtOff);
  int* csr        = (int*)(ws + csrOff);
  int* row        = (int*)(ws + rowOff);
  int* rend       = (int*)(ws + rendOff);
  float* gsum     = (float*)(ws + gsumOff);
  int* bktCur     = (int*)(ws + bktCurOff);
  const bool useFp8 = (ws_size >= needFp8);
  uint8_t* H8     = useFp8 ? (uint8_t*)(ws + h8Off) : nullptr;

  // zero gsum + bucket cursors (contiguous)
  (void)hipMemsetAsync(ws + gsumOff, 0, (60273920 + 1568) - 60208384, stream);

  hipLaunchKernelGGL(bucket_scatter, dim3(kEBlocks), dim3(256), 0, stream, src, dst, bktCur, pairs);
  hipLaunchKernelGGL(bucket_fill, dim3(NB), dim3(256), 0, stream, pairs, bktCur, row, rend, csr);

  hipLaunchKernelGGL(cvt_hw, dim3((kNodes * 32 + kK * kDhid) / 256), dim3(256), 0, stream,
                     h, Ws, Wn, A16, Wt, H8);
  if (useFp8)
    hipLaunchKernelGGL(aggregate8, dim3((kNodes + 3) / 4), dim3(256), 0, stream,
                       H8, A16, row, rend, csr);
  else
    hipLaunchKernelGGL(aggregate, dim3((kNodes + 3) / 4), dim3(256), 0, stream,
                       A16, row, rend, csr);

  hipLaunchKernelGGL(gemm_pool, dim3(kGemmBlocks), dim3(256), 0, stream,
                     A16, Wt, b, gid, gsum);
  hipLaunchKernelGGL(head_kernel, dim3(kGraphs), dim3(64), 0, stream,
                     gsum, Wp, bp, gid, out);
}

// Round 11
// 145.834 us; speedup vs baseline: 61.6544x; 1.1380x over previous
//
#include <hip/hip_runtime.h>
#include <stdint.h>

constexpr int kNodes    = 100000;
constexpr int kEdges    = 1600000;
constexpr int kDin      = 128;
constexpr int kK        = 256;      // concat K = [h | h_neigh]
constexpr int kDhid     = 256;
constexpr int kClasses  = 40;
constexpr int kGraphs   = 64;

constexpr int kBktShift = 8;                       // 256 nodes per bucket
constexpr int NB = (kNodes + 255) >> 8;            // 392 buckets
constexpr int kBktCap = 5120;                      // mean 4082, sigma 64 -> 16 sigma
constexpr int kChunk = 6250;                       // edges per block in scatter
constexpr int kEBlocks = (kEdges + kChunk - 1) / kChunk;  // 256
constexpr int kCvtBlocks = (kNodes * 32 + kK * kDhid) / 256;  // 12756

constexpr int kTPB = 5;                            // row-tiles (32 rows) per gemm block
constexpr int kTiles = kNodes / 32;                // 3125
constexpr int kGemmBlocks = kTiles / kTPB;         // 625

typedef __attribute__((ext_vector_type(8))) short bf8_t;   // 8 x bf16 (4 VGPR)
typedef __attribute__((ext_vector_type(4))) float f4_t;    // mfma C/D
typedef __attribute__((ext_vector_type(2))) float f2_t;

__device__ inline ushort f2bf(float f) {
  uint32_t u = __float_as_uint(f);
  u += 0x7fff + ((u >> 16) & 1);          // RNE
  return (ushort)(u >> 16);
}

// ---- fp8 e4m3 helpers (HW cvt when available; manual fallback) ------------
template <bool HI>
__device__ inline f2_t fp8x2_f32(uint32_t w) {
#if __has_builtin(__builtin_amdgcn_cvt_pk_f32_fp8)
  return __builtin_amdgcn_cvt_pk_f32_fp8(w, HI);
#else
  f2_t r;
  uint32_t b0 = HI ? ((w >> 16) & 0xffu) : (w & 0xffu);
  uint32_t b1 = HI ? (w >> 24) : ((w >> 8) & 0xffu);
  auto dec = [](uint32_t b) -> float {
    uint32_t s = (b & 0x80u) << 24;
    uint32_t em = b & 0x7fu;
    float mag;
    if (em >= 0x08u) {
      uint32_t e = (em >> 3) - 7 + 127;
      mag = __uint_as_float((e << 23) | ((em & 7u) << 20));
    } else {
      mag = (float)em * 0.001953125f;   // em * 2^-9
    }
    return __uint_as_float(s | __float_as_uint(mag));
  };
  r.x = dec(b0); r.y = dec(b1);
  return r;
#endif
}

__device__ inline uint32_t f32_to_e4m3(float f) {
  uint32_t sgn = (__float_as_uint(f) >> 31) << 7;
  float mag = fabsf(f);
  uint32_t r;
  if (mag >= 0.015625f) {               // normal (>= 2^-6)
    uint32_t u = __float_as_uint(mag);
    u += 0x7FFFF + ((u >> 20) & 1);     // RNE to 3 mantissa bits
    int e = (int)(u >> 23) - 127;
    if (e > 8) r = 0x7Eu;               // clamp to 448
    else r = (uint32_t)((e + 7) << 3) | ((u >> 20) & 7u);
  } else {
    float m = mag * 512.f;              // 2^9
    int mi = (int)rintf(m);
    r = (mi > 7) ? 0x08u : (uint32_t)mi;
  }
  return r | sgn;
}

__device__ inline uint32_t pack4_e4m3(float x, float y, float z, float w) {
#if __has_builtin(__builtin_amdgcn_cvt_pk_fp8_f32)
  uint32_t p = __builtin_amdgcn_cvt_pk_fp8_f32(x, y, 0u, false);
  return __builtin_amdgcn_cvt_pk_fp8_f32(z, w, p, true);
#else
  return f32_to_e4m3(x) | (f32_to_e4m3(y) << 8) |
         (f32_to_e4m3(z) << 16) | (f32_to_e4m3(w) << 24);
#endif
}

// ---------------------------------------------------------------------------
// bucket_scatter: fixed-capacity buckets, packed 4B pairs (src<<8 | dlocal).
// ---------------------------------------------------------------------------
__global__ void bucket_scatter(const int* __restrict__ src, const int* __restrict__ dst,
                               int* __restrict__ bktCur, uint32_t* __restrict__ pairs) {
  __shared__ int hist[NB], base[NB], cur[NB];
  for (int i = threadIdx.x; i < NB; i += 256) { hist[i] = 0; cur[i] = 0; }
  __syncthreads();
  int e0 = blockIdx.x * kChunk;
  int e1 = min(e0 + kChunk, kEdges);
  for (int e = e0 + threadIdx.x; e < e1; e += 256)
    atomicAdd(&hist[dst[e] >> kBktShift], 1);
  __syncthreads();
  for (int i = threadIdx.x; i < NB; i += 256)
    base[i] = hist[i] ? atomicAdd(&bktCur[i], hist[i]) : 0;
  __syncthreads();
  for (int e = e0 + threadIdx.x; e < e1; e += 256) {
    int d = dst[e];
    int b = d >> kBktShift;
    int p = atomicAdd(&cur[b], 1);
    pairs[(size_t)b * kBktCap + base[b] + p] = ((uint32_t)src[e] << 8) | (uint32_t)(d & 255);
  }
}

// ---------------------------------------------------------------------------
// fill_cvt: block-routed merge of bucket_fill (first fillBlocks blocks) and
// cvt (h fp32 -> A16 bf16 + H8 fp8; Wt build).  The two halves touch disjoint
// buffers (fill: pairs->csr/row/rend; cvt: h/Ws/Wn->A16/Wt/H8) so they can
// run concurrently in one dispatch.
// ---------------------------------------------------------------------------
__global__ void fill_cvt(const uint32_t* __restrict__ pairs, const int* __restrict__ bktCur,
                         int* __restrict__ row, int* __restrict__ rend, int* __restrict__ csr,
                         const float* __restrict__ h, const float* __restrict__ Ws,
                         const float* __restrict__ Wn, ushort* __restrict__ A16,
                         ushort* __restrict__ Wt, uint8_t* __restrict__ H8,
                         int fillBlocks) {
  __shared__ int deg[256], scn[256], cur[256];
  if ((int)blockIdx.x < fillBlocks) {
    int b = blockIdx.x;
    int t = threadIdx.x;
    int cnt = bktCur[b];
    int e0 = b * kBktCap;
    int nb0 = b << kBktShift;
    deg[t] = 0;
    __syncthreads();
    for (int e = t; e < cnt; e += 256)
      atomicAdd(&deg[pairs[e0 + e] & 255u], 1);
    __syncthreads();
    int d = deg[t];
    scn[t] = d;
    __syncthreads();
#pragma unroll
    for (int off = 1; off < 256; off <<= 1) {
      int u = (t >= off) ? scn[t - off] : 0;
      __syncthreads();
      scn[t] += u;
      __syncthreads();
    }
    int excl = scn[t] - d;
    cur[t] = excl;
    int n = nb0 + t;
    if (n < kNodes) { row[n] = e0 + excl; rend[n] = e0 + scn[t]; }
    __syncthreads();
    for (int e = t; e < cnt; e += 256) {
      uint32_t pr = pairs[e0 + e];
      int p = atomicAdd(&cur[pr & 255u], 1);
      csr[e0 + p] = (int)(pr >> 8);
    }
  } else {
    int t = ((int)blockIdx.x - fillBlocks) * 256 + threadIdx.x;
    const int hN = kNodes * 32;          // 3,200,000 float4-quads
    if (t < hN) {
      int n = t >> 5;
      int c4 = (t & 31) * 4;
      float4 v = *reinterpret_cast<const float4*>(h + (size_t)n * kDin + c4);
      ushort4 o;
      o.x = f2bf(v.x); o.y = f2bf(v.y); o.z = f2bf(v.z); o.w = f2bf(v.w);
      *reinterpret_cast<ushort4*>(A16 + (size_t)n * kK + c4) = o;
      *reinterpret_cast<uint32_t*>(H8 + (size_t)n * kDin + c4) =
          pack4_e4m3(v.x, v.y, v.z, v.w);
    } else {
      int u = t - hN;                    // 0 .. 65535
      int j = u & 255;
      int k = u >> 8;
      float v = (k < 128) ? Ws[(size_t)k * kDhid + j] : Wn[(size_t)(k - 128) * kDhid + j];
      Wt[(size_t)j * kK + k] = f2bf(v);
    }
  }
}

// ---------------------------------------------------------------------------
// aggregate8 v3: group-per-node.  4 x 16-lane groups per wave, each group
// owns ONE node and walks its whole neighbor list (16 lanes x 8B = full
// 128B fp8 row).  No cross-group reduction, no shuffles; group stores its
// node's 256B bf16 output directly.  unroll 4 => 16 rows in flight/wave.
// ---------------------------------------------------------------------------
__global__ void aggregate8(const uint8_t* __restrict__ H8, ushort* __restrict__ A16,
                           const int* __restrict__ row, const int* __restrict__ rend,
                           const int* __restrict__ csr) {
  int wv = (blockIdx.x * 256 + threadIdx.x) >> 6;   // wave id, 25000 waves
  int lane = threadIdx.x & 63;
  int grp = lane >> 4;      // 0..3: node slot
  int sub = lane & 15;      // 0..15: 8B column chunk
  int n = wv * 4 + grp;                             // exact: 25000*4 = 100000
  int s0 = row[n], s1 = rend[n];
  float a0 = 0.f, a1 = 0.f, a2 = 0.f, a3 = 0.f, a4 = 0.f, a5 = 0.f, a6 = 0.f, a7 = 0.f;
#pragma unroll 4
  for (int i = s0; i < s1; ++i) {
    int s = csr[i];
    uint2 v = *reinterpret_cast<const uint2*>(H8 + (size_t)s * kDin + sub * 8);
    f2_t l0 = fp8x2_f32<false>(v.x), h0 = fp8x2_f32<true>(v.x);
    f2_t l1 = fp8x2_f32<false>(v.y), h1 = fp8x2_f32<true>(v.y);
    a0 += l0.x; a1 += l0.y; a2 += h0.x; a3 += h0.y;
    a4 += l1.x; a5 += l1.y; a6 += h1.x; a7 += h1.y;
  }
  float rd = 1.f / fmaxf((float)(s1 - s0), 1.f);
  uint4 o;
  o.x = (uint32_t)f2bf(a0 * rd) | ((uint32_t)f2bf(a1 * rd) << 16);
  o.y = (uint32_t)f2bf(a2 * rd) | ((uint32_t)f2bf(a3 * rd) << 16);
  o.z = (uint32_t)f2bf(a4 * rd) | ((uint32_t)f2bf(a5 * rd) << 16);
  o.w = (uint32_t)f2bf(a6 * rd) | ((uint32_t)f2bf(a7 * rd) << 16);
  *reinterpret_cast<uint4*>((char*)A16 + (size_t)n * 512 + 256 + sub * 16) = o;
}

// ---------------------------------------------------------------------------
// gemm_pool: W-stationary streaming (unchanged).
// ---------------------------------------------------------------------------
__global__ __launch_bounds__(256, 2)
void gemm_pool(const ushort* __restrict__ A16, const ushort* __restrict__ Wt,
               const float* __restrict__ bias, const int* __restrict__ gid,
               float* __restrict__ gsum) {
  __shared__ ushort Abuf[2][32 * 256];   // 2 x 16 KB
  const int tid  = threadIdx.x;
  const int lane = tid & 63;
  const int wave = tid >> 6;
  const int lhi = lane >> 4;
  const int llo = lane & 15;

  bf8_t bfr[4][8];
#pragma unroll
  for (int nf = 0; nf < 4; ++nf) {
    const char* wrow = (const char*)Wt + (size_t)(wave * 64 + nf * 16 + llo) * 512 + lhi * 16;
#pragma unroll
    for (int kk = 0; kk < 8; ++kk)
      bfr[nf][kk] = *reinterpret_cast<const bf8_t*>(wrow + kk * 64);
  }
  float bv[4];
#pragma unroll
  for (int nf = 0; nf < 4; ++nf) bv[nf] = bias[wave * 64 + nf * 16 + llo];

  auto stage = [&](int buf, int tile) {
#pragma unroll
    for (int i = 0; i < 4; ++i) {
      int r = i * 8 + (tid >> 5);
      int wb = (tid & 31) * 16;
      size_t gsrc = ((size_t)tile * 32 + r) * 512 + (size_t)(wb ^ ((r & 7) << 4));
      uint32_t ldst = (uint32_t)(i * 4096 + tid * 16);
      __builtin_amdgcn_global_load_lds(
          (const __attribute__((address_space(1))) uint32_t*)((const char*)A16 + gsrc),
          (__attribute__((address_space(3))) uint32_t*)((char*)&Abuf[buf][0] + ldst),
          16, 0, 0);
    }
  };

  const int t0 = blockIdx.x * kTPB;
  stage(0, t0);
  __syncthreads();

  float pooled[4] = {0.f, 0.f, 0.f, 0.f};
  int cur_g = gid[t0 * 32];

  for (int ti = 0; ti < kTPB; ++ti) {
    int tile = t0 + ti;
    if (ti + 1 < kTPB) stage((ti + 1) & 1, tile + 1);

    f4_t acc[2][4];
#pragma unroll
    for (int mf = 0; mf < 2; ++mf)
#pragma unroll
      for (int nf = 0; nf < 4; ++nf) acc[mf][nf] = (f4_t)0.f;
    const char* abase = (const char*)&Abuf[ti & 1][0];
    const int swz = (llo & 7) << 4;
#pragma unroll
    for (int kk = 0; kk < 8; ++kk) {
      int kb = kk * 64 + lhi * 16;
      bf8_t x0 = *reinterpret_cast<const bf8_t*>(abase + llo * 512 + (kb ^ swz));
      bf8_t x1 = *reinterpret_cast<const bf8_t*>(abase + (16 + llo) * 512 + (kb ^ swz));
#pragma unroll
      for (int nf = 0; nf < 4; ++nf) {
        acc[0][nf] = __builtin_amdgcn_mfma_f32_16x16x32_bf16(x0, bfr[nf][kk], acc[0][nf], 0, 0, 0);
        acc[1][nf] = __builtin_amdgcn_mfma_f32_16x16x32_bf16(x1, bfr[nf][kk], acc[1][nf], 0, 0, 0);
      }
    }

    int base = tile * 32;
    int gA = gid[base], gB = gid[base + 31];
    if (gA == gB) {
      if (gA != cur_g) {
#pragma unroll
        for (int nf = 0; nf < 4; ++nf) {
          if (pooled[nf] != 0.f)
            atomicAdd(&gsum[cur_g * kDhid + wave * 64 + nf * 16 + llo], pooled[nf]);
          pooled[nf] = 0.f;
        }
        cur_g = gA;
      }
#pragma unroll
      for (int nf = 0; nf < 4; ++nf) {
        float s = 0.f;
#pragma unroll
        for (int mf = 0; mf < 2; ++mf)
#pragma unroll
          for (int q = 0; q < 4; ++q) s += fmaxf(acc[mf][nf][q] + bv[nf], 0.f);
        pooled[nf] += s;
      }
    } else {
#pragma unroll
      for (int mf = 0; mf < 2; ++mf)
#pragma unroll
        for (int q = 0; q < 4; ++q) {
          int r = base + mf * 16 + lhi * 4 + q;
          int g = gid[r];
#pragma unroll
          for (int nf = 0; nf < 4; ++nf) {
            float v = fmaxf(acc[mf][nf][q] + bv[nf], 0.f);
            if (v != 0.f) atomicAdd(&gsum[g * kDhid + wave * 64 + nf * 16 + llo], v);
          }
        }
    }
    __syncthreads();
  }

#pragma unroll
  for (int nf = 0; nf < 4; ++nf)
    if (pooled[nf] != 0.f)
      atomicAdd(&gsum[cur_g * kDhid + wave * 64 + nf * 16 + llo], pooled[nf]);
}

// ---------------------------------------------------------------------------
// head: out[g] = (gsum[g]/cnt[g]) @ Wp + bp, cnt via binary search on gid.
// ---------------------------------------------------------------------------
__global__ void head_kernel(const float* __restrict__ gsum,
                            const float* __restrict__ Wp,
                            const float* __restrict__ bp,
                            const int* __restrict__ gid,
                            float* __restrict__ out) {
  int g = blockIdx.x;
  int c = threadIdx.x;
  int lo0 = 0, hi0 = kNodes;
  while (lo0 < hi0) { int m = (lo0 + hi0) >> 1; if (gid[m] < g) lo0 = m + 1; else hi0 = m; }
  int lo1 = lo0, hi1 = kNodes;
  while (lo1 < hi1) { int m = (lo1 + hi1) >> 1; if (gid[m] < g + 1) lo1 = m + 1; else hi1 = m; }
  float rc = 1.0f / fmaxf((float)(lo1 - lo0), 1.0f);
  if (c < kClasses) {
    float acc = bp[c];
    for (int k = 0; k < kDhid; ++k)
      acc += gsum[g * kDhid + k] * rc * Wp[k * kClasses + c];
    out[g * kClasses + c] = acc;
  }
}

// ---------------------------------------------------------------------------
extern "C" void kernel_launch(void* const* d_in, const int* in_sizes, int n_in,
                              void* d_out, int out_size, void* d_ws, size_t ws_size,
                              hipStream_t stream) {
  const float* h  = (const float*)d_in[0];
  const float* Ws = (const float*)d_in[1];
  const float* Wn = (const float*)d_in[2];
  const float* b  = (const float*)d_in[3];
  const float* Wp = (const float*)d_in[4];
  const float* bp = (const float*)d_in[5];
  const int* src  = (const int*)d_in[6];
  const int* dst  = (const int*)d_in[7];
  const int* gid  = (const int*)d_in[8];
  float* out = (float*)d_out;

  char* ws = (char*)d_ws;
  const size_t a16Off    = 0;             // 100000*256*2 = 51,200,000
  const size_t wtOff     = 51249152;      // 131,072
  const size_t csrOff    = 51380224;      // 392*5120*4 = 8,028,160
  const size_t rowOff    = 59408384;      // 400,000
  const size_t rendOff   = 59808384;      // 400,000
  const size_t gsumOff   = 60208384;      // 65,536
  const size_t bktCurOff = 60273920;      // 1,568
  const size_t h8Off     = 60275712;      // 12,800,000 (fp8 gather table)
  const size_t pairsOff  = 73075712;      // 8,028,160 (non-aliased, big-ws path)
  const size_t needBig   = pairsOff + 8028160;   // 81,103,872
  ushort* A16     = (ushort*)(ws + a16Off);
  ushort* Wt      = (ushort*)(ws + wtOff);
  int* csr        = (int*)(ws + csrOff);
  int* row        = (int*)(ws + rowOff);
  int* rend       = (int*)(ws + rendOff);
  float* gsum     = (float*)(ws + gsumOff);
  int* bktCur     = (int*)(ws + bktCurOff);
  uint8_t* H8     = (uint8_t*)(ws + h8Off);
  const bool bigWs = (ws_size >= needBig);
  // small-ws fallback: pairs aliases A16 (then fill must finish before cvt)
  uint32_t* pairs = bigWs ? (uint32_t*)(ws + pairsOff) : (uint32_t*)(ws + a16Off);

  // zero gsum + bucket cursors (contiguous 67,104 B)
  (void)hipMemsetAsync(ws + gsumOff, 0, (60273920 + 1568) - 60208384, stream);

  hipLaunchKernelGGL(bucket_scatter, dim3(kEBlocks), dim3(256), 0, stream, src, dst, bktCur, pairs);

  if (bigWs) {
    hipLaunchKernelGGL(fill_cvt, dim3(NB + kCvtBlocks), dim3(256), 0, stream,
                       pairs, bktCur, row, rend, csr, h, Ws, Wn, A16, Wt, H8, NB);
  } else {
    hipLaunchKernelGGL(fill_cvt, dim3(NB), dim3(256), 0, stream,
                       pairs, bktCur, row, rend, csr, h, Ws, Wn, A16, Wt, H8, NB);
    hipLaunchKernelGGL(fill_cvt, dim3(kCvtBlocks), dim3(256), 0, stream,
                       pairs, bktCur, row, rend, csr, h, Ws, Wn, A16, Wt, H8, 0);
  }

  hipLaunchKernelGGL(aggregate8, dim3(kNodes / 16), dim3(256), 0, stream,
                     H8, A16, row, rend, csr);

  hipLaunchKernelGGL(gemm_pool, dim3(kGemmBlocks), dim3(256), 0, stream,
                     A16, Wt, b, gid, gsum);
  hipLaunchKernelGGL(head_kernel, dim3(kGraphs), dim3(64), 0, stream,
                     gsum, Wp, bp, gid, out);
}